// Round 1
// baseline (232.102 us; speedup 1.0000x reference)
//
#include <hip/hip_runtime.h>
#include <stdint.h>

typedef short s16x8 __attribute__((ext_vector_type(8)));
typedef float f32x4 __attribute__((ext_vector_type(4)));

__device__ __forceinline__ float bits2f(unsigned short u) {
    union { unsigned int i; float f; } c; c.i = ((unsigned int)u) << 16; return c.f;
}
__device__ __forceinline__ unsigned short f2bits(float f) {
    union { float f; unsigned int i; } c; c.f = f;
    unsigned int x = c.i;
    unsigned int r = (x + 0x7FFFu + ((x >> 16) & 1u)) >> 16;
    return (unsigned short)r;
}
__device__ __forceinline__ unsigned int pack2(float a, float b) {
    return (unsigned int)f2bits(a) | ((unsigned int)f2bits(b) << 16);
}

// ---------------------------------------------------------------------------
// f32 -> bf16 bulk convert; n8 = n/8  (fallback path only)
__global__ __launch_bounds__(256) void k_cvt(
    const float* __restrict__ src, unsigned short* __restrict__ dst, int n8)
{
    int i = blockIdx.x * 256 + threadIdx.x;
    if (i >= n8) return;
    const float* s = src + (size_t)i * 8;
    float4 a = *(const float4*)s, b = *(const float4*)(s + 4);
    unsigned int q[4] = { pack2(a.x, a.y), pack2(a.z, a.w), pack2(b.x, b.y), pack2(b.z, b.w) };
    *(s16x8*)(dst + (size_t)i * 8) = *(s16x8*)q;
}

// ---------------------------------------------------------------------------
// transpose (WqT only, 256x256 bf16): dst[dr][c] = src[c][dr]  (fallback only)
__global__ __launch_bounds__(256) void k_transpose(
    const unsigned short* __restrict__ src, unsigned short* __restrict__ dst,
    int RS, int DS)
{
    int dr = blockIdx.x * 256 + threadIdx.x;
    int c0 = blockIdx.y * 8;
    __align__(16) unsigned short tmp[8];
#pragma unroll
    for (int j = 0; j < 8; ++j) tmp[j] = src[(size_t)(c0 + j) * RS + dr];
    *(s16x8*)(dst + (size_t)dr * DS + c0) = *(s16x8*)tmp;
}

// ---------------------------------------------------------------------------
// merged weight prep: wb = bf16(w_qkv) [768x256]; wob = bf16(w_out) [256x256];
// WqT[c][hd] = bf16(w_qkv[hd][c]) for hd<256. grid 160 blocks x 256.
__global__ __launch_bounds__(256) void k_prepw(
    const float* __restrict__ wqkv, const float* __restrict__ wout,
    unsigned short* __restrict__ wb, unsigned short* __restrict__ wob,
    unsigned short* __restrict__ WqT)
{
    int i = blockIdx.x * 256 + threadIdx.x;
    if (i < 32768) {
        const float* s; unsigned short* d; int j;
        if (i < 24576) { s = wqkv; d = wb; j = i; }
        else           { s = wout; d = wob; j = i - 24576; }
        const float* sp = s + (size_t)j * 8;
        float4 a = *(const float4*)sp, b = *(const float4*)(sp + 4);
        unsigned int q[4] = { pack2(a.x, a.y), pack2(a.z, a.w), pack2(b.x, b.y), pack2(b.z, b.w) };
        *(s16x8*)(d + (size_t)j * 8) = *(s16x8*)q;
    } else {
        int j = i - 32768;                 // [0, 8192)
        int dr = j & 255, c0 = (j >> 8) * 8;
        __align__(16) unsigned short tmp[8];
#pragma unroll
        for (int jj = 0; jj < 8; ++jj)
            tmp[jj] = f2bits(wqkv[(size_t)(c0 + jj) * 256 + dr]);
        *(s16x8*)(WqT + (size_t)dr * 256 + c0) = *(s16x8*)tmp;
    }
}

// ---------------------------------------------------------------------------
// x [b][256 c][4096 n] f32  ->  xT [b][4096 n][256 c] bf16
// block: one 64-n slice of one batch, all 256 c. LDS tile [n][c].
__global__ __launch_bounds__(256) void k_prep(
    const float* __restrict__ x, unsigned short* __restrict__ xT)
{
    __shared__ unsigned short Ts[64][264];   // rows 528B (16B-aligned), pad vs bank collisions
    int b = blockIdx.y, n0 = blockIdx.x * 64, t = threadIdx.x;
    const float* xb = x + (size_t)b * 1048576;
#pragma unroll
    for (int i = 0; i < 16; ++i) {
        int idx = t + i * 256;               // 0..4095
        int c = idx >> 4, nq = idx & 15;
        float4 v = *(const float4*)(xb + (size_t)c * 4096 + n0 + nq * 4);
        float vv[4] = { v.x, v.y, v.z, v.w };
#pragma unroll
        for (int e = 0; e < 4; ++e) {
            int ee = (e + c) & 3;            // rotate store order: spread LDS banks
            Ts[nq * 4 + ee][c] = f2bits(vv[ee]);
        }
    }
    __syncthreads();
    unsigned short* xTb = xT + (size_t)b * 1048576 + (size_t)n0 * 256;
#pragma unroll
    for (int i = 0; i < 8; ++i) {
        int idx = t + i * 256;               // 0..2047
        int nl = idx >> 5, cg = (idx & 31) * 8;
        *(s16x8*)(xTb + (size_t)nl * 256 + cg) = *(const s16x8*)&Ts[nl][cg];
    }
}

// ---------------------------------------------------------------------------
// gemm_bt: C[m][n] = sum_k A[m][k] * Bt[n][k]; A bf16, Bt bf16 or f32 (BF32).
// BM=BN=128, BK=64, block=256. bz: b=bz&15, kc=bz>>4; K-origin = kc*Kstep.
// EPI==0: C bf16.  EPI==1: C f32, C = gamma[m]*(acc+bias[m]) + Xres[m][n].
template <int BF32, int EPI>
__global__ __launch_bounds__(256) void gemm_bt(
    const unsigned short* __restrict__ A, const void* __restrict__ Bt,
    void* __restrict__ C,
    int K, int Kstep, int lda, int ldb, int ldc,
    long Abs, long Bbs, long Cbs,
    const float* __restrict__ Xres,
    const float* __restrict__ gamma,
    const float* __restrict__ bias)
{
    __shared__ unsigned short As[128][72];
    __shared__ unsigned short Bs[128][72];
    int bz = blockIdx.z;
    int b = bz & 15, kc = bz >> 4;
    int m0 = blockIdx.y * 128, n0 = blockIdx.x * 128;
    const unsigned short* Ab = A + (size_t)b * Abs + (size_t)m0 * lda + (size_t)kc * Kstep;
    size_t boff = (size_t)b * Bbs + (size_t)n0 * ldb + (size_t)kc * Kstep;
    int t = threadIdx.x;
    int w = t >> 6, l = t & 63, lm = l & 15, lq = l >> 4;
    int mw = (w >> 1) * 64, nw = (w & 1) * 64;

    f32x4 acc[4][4];
    f32x4 zero = {0.f, 0.f, 0.f, 0.f};
#pragma unroll
    for (int i = 0; i < 4; ++i)
#pragma unroll
        for (int j = 0; j < 4; ++j) acc[i][j] = zero;

    for (int kk = 0; kk < K; kk += 64) {
#pragma unroll
        for (int i = 0; i < 4; ++i) {
            int idx = t + i * 256;
            int r = idx >> 3, ch = idx & 7;
            *(s16x8*)&As[r][ch * 8] = *(const s16x8*)(Ab + (size_t)r * lda + kk + ch * 8);
            if (BF32) {
                const float* bp = (const float*)Bt + boff + (size_t)r * ldb + kk + ch * 8;
                float4 v0 = *(const float4*)bp, v1 = *(const float4*)(bp + 4);
                unsigned int q[4] = { pack2(v0.x, v0.y), pack2(v0.z, v0.w),
                                      pack2(v1.x, v1.y), pack2(v1.z, v1.w) };
                *(s16x8*)&Bs[r][ch * 8] = *(s16x8*)q;
            } else {
                const unsigned short* bp = (const unsigned short*)Bt + boff + (size_t)r * ldb + kk + ch * 8;
                *(s16x8*)&Bs[r][ch * 8] = *(const s16x8*)bp;
            }
        }
        __syncthreads();
#pragma unroll
        for (int ks = 0; ks < 2; ++ks) {
            s16x8 af[4], bfr[4];
#pragma unroll
            for (int mi = 0; mi < 4; ++mi) af[mi]  = *(const s16x8*)&As[mw + mi * 16 + lm][ks * 32 + lq * 8];
#pragma unroll
            for (int ni = 0; ni < 4; ++ni) bfr[ni] = *(const s16x8*)&Bs[nw + ni * 16 + lm][ks * 32 + lq * 8];
#pragma unroll
            for (int mi = 0; mi < 4; ++mi)
#pragma unroll
                for (int ni = 0; ni < 4; ++ni)
                    acc[mi][ni] = __builtin_amdgcn_mfma_f32_16x16x32_bf16(af[mi], bfr[ni], acc[mi][ni], 0, 0, 0);
        }
        __syncthreads();
    }

    if (EPI == 0) {
        unsigned short* Cb = (unsigned short*)C + (size_t)bz * Cbs;
#pragma unroll
        for (int mi = 0; mi < 4; ++mi)
#pragma unroll
            for (int r = 0; r < 4; ++r) {
                int m = m0 + mw + mi * 16 + lq * 4 + r;
#pragma unroll
                for (int ni = 0; ni < 4; ++ni) {
                    int n = n0 + nw + ni * 16 + lm;
                    Cb[(size_t)m * ldc + n] = f2bits(acc[mi][ni][r]);
                }
            }
    } else {
        float* Cb = (float*)C + (size_t)bz * Cbs;
        const float* Xb = Xres + (size_t)bz * Cbs;
#pragma unroll
        for (int mi = 0; mi < 4; ++mi)
#pragma unroll
            for (int r = 0; r < 4; ++r) {
                int m = m0 + mw + mi * 16 + lq * 4 + r;
                float g = gamma[m], bo = bias[m];
#pragma unroll
                for (int ni = 0; ni < 4; ++ni) {
                    int n = n0 + nw + ni * 16 + lm;
                    size_t idx = (size_t)m * ldc + n;
                    Cb[idx] = g * (acc[mi][ni][r] + bo) + Xb[idx];
                }
            }
    }
}

// ---------------------------------------------------------------------------
// gemm_bn (fallback path only): C[m][n] = sum_k A[m][k] * B[k][n]
template <int EPI>
__global__ __launch_bounds__(256) void gemm_bn(
    const unsigned short* __restrict__ A, const float* __restrict__ B,
    void* __restrict__ C,
    int K, int lda, int ldb, int ldc,
    long Abs, long Bbs, long Cbs,
    const float* __restrict__ Xres,
    const float* __restrict__ gamma,
    const float* __restrict__ bias)
{
    __shared__ unsigned short As[128][72];
    __shared__ unsigned short Bs[64][130];
    int bz = blockIdx.z;
    int m0 = blockIdx.y * 128, n0 = blockIdx.x * 128;
    const unsigned short* Ab = A + (size_t)bz * Abs + (size_t)m0 * lda;
    const float* Bb = B + (size_t)bz * Bbs + n0;
    int t = threadIdx.x;
    int w = t >> 6, l = t & 63, lm = l & 15, lq = l >> 4;
    int mw = (w >> 1) * 64, nw = (w & 1) * 64;

    f32x4 acc[4][4];
    f32x4 zero = {0.f, 0.f, 0.f, 0.f};
#pragma unroll
    for (int i = 0; i < 4; ++i)
#pragma unroll
        for (int j = 0; j < 4; ++j) acc[i][j] = zero;

    for (int kk = 0; kk < K; kk += 64) {
#pragma unroll
        for (int i = 0; i < 4; ++i) {
            int idx = t + i * 256;
            int r = idx >> 3, ch = idx & 7;
            *(s16x8*)&As[r][ch * 8] = *(const s16x8*)(Ab + (size_t)r * lda + kk + ch * 8);
        }
#pragma unroll
        for (int i = 0; i < 4; ++i) {
            int idx = t + i * 256;
            int c = idx >> 4, cc = idx & 15;
            const float* bp = Bb + (size_t)(kk + c) * ldb + cc * 8;
            float4 v0 = *(const float4*)bp, v1 = *(const float4*)(bp + 4);
            unsigned int* q = (unsigned int*)&Bs[c][cc * 8];
            q[0] = pack2(v0.x, v0.y); q[1] = pack2(v0.z, v0.w);
            q[2] = pack2(v1.x, v1.y); q[3] = pack2(v1.z, v1.w);
        }
        __syncthreads();
#pragma unroll
        for (int ks = 0; ks < 2; ++ks) {
            s16x8 af[4];
#pragma unroll
            for (int mi = 0; mi < 4; ++mi) af[mi] = *(const s16x8*)&As[mw + mi * 16 + lm][ks * 32 + lq * 8];
#pragma unroll
            for (int ni = 0; ni < 4; ++ni) {
                s16x8 bfr;
#pragma unroll
                for (int j = 0; j < 8; ++j) bfr[j] = (short)Bs[ks * 32 + lq * 8 + j][nw + ni * 16 + lm];
#pragma unroll
                for (int mi = 0; mi < 4; ++mi)
                    acc[mi][ni] = __builtin_amdgcn_mfma_f32_16x16x32_bf16(af[mi], bfr, acc[mi][ni], 0, 0, 0);
            }
        }
        __syncthreads();
    }

#pragma unroll
    for (int mi = 0; mi < 4; ++mi)
#pragma unroll
        for (int r = 0; r < 4; ++r) {
            int m = m0 + mw + mi * 16 + lq * 4 + r;
            float g = 0.f, bo = 0.f;
            if (EPI == 1) { g = gamma[m]; bo = bias[m]; }
#pragma unroll
            for (int ni = 0; ni < 4; ++ni) {
                int n = n0 + nw + ni * 16 + lm;
                size_t idx = (size_t)m * ldc + n;
                float v = acc[mi][ni][r];
                if (EPI == 1) {
                    float* Cb = (float*)C + (size_t)bz * Cbs;
                    Cb[idx] = g * (v + bo) + Xres[(size_t)bz * Cbs + idx];
                } else {
                    unsigned short* Cb = (unsigned short*)C + (size_t)bz * Cbs;
                    Cb[idx] = f2bits(v);
                }
            }
        }
}

// ---------------------------------------------------------------------------
// softmax over n (4096) for each of 4096 rows of kbuf (bf16)
__global__ __launch_bounds__(256) void k_softmax(unsigned short* __restrict__ kbuf)
{
    unsigned short* p = kbuf + (size_t)blockIdx.x * 4096;
    int t = threadIdx.x;
    __shared__ float red[4];

    s16x8 r0 = *(const s16x8*)(p + t * 16);
    s16x8 r1 = *(const s16x8*)(p + t * 16 + 8);
    float v[16];
    float m = -1e30f;
#pragma unroll
    for (int i = 0; i < 8; ++i) { v[i] = bits2f((unsigned short)r0[i]); v[8 + i] = bits2f((unsigned short)r1[i]); }
#pragma unroll
    for (int i = 0; i < 16; ++i) m = fmaxf(m, v[i]);
#pragma unroll
    for (int off = 32; off >= 1; off >>= 1) m = fmaxf(m, __shfl_xor(m, off));
    if ((t & 63) == 0) red[t >> 6] = m;
    __syncthreads();
    m = fmaxf(fmaxf(red[0], red[1]), fmaxf(red[2], red[3]));
    __syncthreads();

    float s = 0.f;
#pragma unroll
    for (int i = 0; i < 16; ++i) { v[i] = __expf(v[i] - m); s += v[i]; }
#pragma unroll
    for (int off = 32; off >= 1; off >>= 1) s += __shfl_xor(s, off);
    if ((t & 63) == 0) red[t >> 6] = s;
    __syncthreads();
    s = red[0] + red[1] + red[2] + red[3];
    float inv = 1.0f / s;

    __align__(16) unsigned short otmp[16];
#pragma unroll
    for (int i = 0; i < 16; ++i) otmp[i] = f2bits(v[i] * inv);
    *(s16x8*)(p + t * 16) = *(s16x8*)(otmp);
    *(s16x8*)(p + t * 16 + 8) = *(s16x8*)(otmp + 8);
}

// ---------------------------------------------------------------------------
// G[b][i] = sum_{kc<8} Gp[kc*16+b][i]
__global__ __launch_bounds__(256) void k_gred(
    const unsigned short* __restrict__ Gp, unsigned short* __restrict__ G)
{
    int gid = blockIdx.x * 256 + threadIdx.x;   // [0, 131072)
    int b = gid >> 13;
    size_t i8 = (size_t)(gid & 8191) * 8;
    float s[8] = {0.f, 0.f, 0.f, 0.f, 0.f, 0.f, 0.f, 0.f};
#pragma unroll
    for (int kc = 0; kc < 8; ++kc) {
        s16x8 v = *(const s16x8*)(Gp + (size_t)(kc * 16 + b) * 65536 + i8);
#pragma unroll
        for (int j = 0; j < 8; ++j) s[j] += bits2f((unsigned short)v[j]);
    }
    __align__(16) unsigned short tmp[8];
#pragma unroll
    for (int j = 0; j < 8; ++j) tmp[j] = f2bits(s[j]);
    *(s16x8*)(G + (size_t)b * 65536 + i8) = *(s16x8*)tmp;
}

// ---------------------------------------------------------------------------
// per (b,h): ctx[d][e] = sum_c G[b][h*64+d][c] * Wv[h*64+e][c]  (K=256)
// then      W2[b][o][h*64+d] = sum_e w_out[o][h*64+e] * ctx[d][e] (K=64)
__global__ __launch_bounds__(256) void k_ctxw2(
    const unsigned short* __restrict__ G, const unsigned short* __restrict__ wb,
    const unsigned short* __restrict__ wob, unsigned short* __restrict__ W2)
{
    __shared__ unsigned short ctxs[64][72];
    int h = blockIdx.x, b = blockIdx.y;
    int t = threadIdx.x, w = t >> 6, l = t & 63, lm = l & 15, lq = l >> 4;
    const unsigned short* Gb = G + (size_t)b * 65536 + (size_t)(h * 64) * 256;
    const unsigned short* Wv = wb + 131072 + (size_t)(h * 64) * 256;
    f32x4 zero = {0.f, 0.f, 0.f, 0.f};

    f32x4 acc[4];
#pragma unroll
    for (int i = 0; i < 4; ++i) acc[i] = zero;
    for (int kk = 0; kk < 256; kk += 32) {
        s16x8 a = *(const s16x8*)(Gb + (size_t)(w * 16 + lm) * 256 + kk + lq * 8);
#pragma unroll
        for (int ni = 0; ni < 4; ++ni) {
            s16x8 bb = *(const s16x8*)(Wv + (size_t)(ni * 16 + lm) * 256 + kk + lq * 8);
            acc[ni] = __builtin_amdgcn_mfma_f32_16x16x32_bf16(a, bb, acc[ni], 0, 0, 0);
        }
    }
#pragma unroll
    for (int ni = 0; ni < 4; ++ni)
#pragma unroll
        for (int r = 0; r < 4; ++r)
            ctxs[w * 16 + lq * 4 + r][ni * 16 + lm] = f2bits(acc[ni][r]);
    __syncthreads();

    f32x4 acc2[4][4];
#pragma unroll
    for (int i = 0; i < 4; ++i)
#pragma unroll
        for (int j = 0; j < 4; ++j) acc2[i][j] = zero;
#pragma unroll
    for (int ks = 0; ks < 2; ++ks) {
        s16x8 af[4], bfr[4];
#pragma unroll
        for (int mi = 0; mi < 4; ++mi)
            af[mi] = *(const s16x8*)(wob + (size_t)(w * 64 + mi * 16 + lm) * 256 + h * 64 + ks * 32 + lq * 8);
#pragma unroll
        for (int ni = 0; ni < 4; ++ni) bfr[ni] = *(const s16x8*)&ctxs[ni * 16 + lm][ks * 32 + lq * 8];
#pragma unroll
        for (int mi = 0; mi < 4; ++mi)
#pragma unroll
            for (int ni = 0; ni < 4; ++ni)
                acc2[mi][ni] = __builtin_amdgcn_mfma_f32_16x16x32_bf16(af[mi], bfr[ni], acc2[mi][ni], 0, 0, 0);
    }
    unsigned short* W2b = W2 + (size_t)b * 65536;
#pragma unroll
    for (int mi = 0; mi < 4; ++mi)
#pragma unroll
        for (int r = 0; r < 4; ++r) {
            int o = w * 64 + mi * 16 + lq * 4 + r;
#pragma unroll
            for (int ni = 0; ni < 4; ++ni)
                W2b[(size_t)o * 256 + h * 64 + ni * 16 + lm] = f2bits(acc2[mi][ni][r]);
        }
}

// ---------------------------------------------------------------------------
extern "C" void kernel_launch(void* const* d_in, const int* in_sizes, int n_in,
                              void* d_out, int out_size, void* d_ws, size_t ws_size,
                              hipStream_t stream)
{
    (void)in_sizes; (void)n_in; (void)out_size;
    const float* x      = (const float*)d_in[0]; // [16][256][4096] f32
    const float* w_qkv  = (const float*)d_in[1]; // [768][256] f32
    const float* w_out  = (const float*)d_in[2]; // [256][256] f32
    const float* b_out  = (const float*)d_in[3]; // [256] f32
    const float* gamma  = (const float*)d_in[4]; // [256] f32

    char* ws = (char*)d_ws;
    const size_t NEED = 40501248;

    if (ws_size >= NEED) {
        // ---- new path: all big GEMMs via gemm_bt on bf16 xT ----
        // ws layout (40,501,248 B)
        unsigned short* xT  = (unsigned short*)ws;                    // [16][4096][256] bf16 = 33,554,432
        unsigned short* G   = (unsigned short*)(ws + 33554432);       //  2,097,152
        unsigned short* W2  = (unsigned short*)(ws + 35651584);       //  2,097,152
        unsigned short* W3  = (unsigned short*)(ws + 37748736);       //  2,097,152
        unsigned short* WqT = (unsigned short*)(ws + 39845888);       //    131,072
        unsigned short* wb  = (unsigned short*)(ws + 39976960);       //    393,216
        unsigned short* wob = (unsigned short*)(ws + 40370176);       //    131,072
        // d_out (64MB) doubles as scratch until K5 rewrites it all:
        unsigned short* kbuf = (unsigned short*)d_out;                        // lower 32MB
        unsigned short* Gp   = (unsigned short*)((char*)d_out + 33554432);    // upper, 16MB (dead after k_gred)

        // weights: wb/wob bf16 + WqT (direct from f32, same rounding)
        k_prepw<<<dim3(160), 256, 0, stream>>>(w_qkv, w_out, wb, wob, WqT);

        // xT = transpose(x) in bf16
        k_prep<<<dim3(64, 16), 256, 0, stream>>>(x, xT);

        // K1: k = Wk @ x  ==  gemm_bt(A=Wk, Bt=xT)   (M=256,N=4096,K=256)
        gemm_bt<0, 0><<<dim3(32, 2, 16), 256, 0, stream>>>(
            wb + 65536, xT, kbuf, 256, 0, 256, 256, 4096,
            0L, 1048576L, 1048576L, nullptr, nullptr, nullptr);

        // K2: softmax rows of k
        k_softmax<<<dim3(4096), 256, 0, stream>>>(kbuf);

        // KG: Gp[kc*16+b] = softk_b[:, chunk] @ x_b[:, chunk]^T  (K-split x8)
        gemm_bt<1, 0><<<dim3(2, 2, 128), 256, 0, stream>>>(
            kbuf, x, Gp, 512, 512, 4096, 4096, 256,
            1048576L, 1048576L, 65536L, nullptr, nullptr, nullptr);

        // G = sum_kc Gp
        k_gred<<<dim3(512), 256, 0, stream>>>(Gp, G);

        // ctx + W2 fused per (b,h)
        k_ctxw2<<<dim3(4, 16), 256, 0, stream>>>(G, wb, wob, W2);

        // W3[b] = W2[b] @ Wq
        gemm_bt<0, 0><<<dim3(2, 2, 16), 256, 0, stream>>>(
            W2, WqT, W3, 256, 0, 256, 256, 256,
            65536L, 0L, 65536L, nullptr, nullptr, nullptr);

        // K5: out(f32) = gamma*(W3 @ x + b_out) + x   ==  gemm_bt(A=W3, Bt=xT) + EPI
        gemm_bt<0, 1><<<dim3(32, 2, 16), 256, 0, stream>>>(
            W3, xT, d_out, 256, 0, 256, 256, 4096,
            65536L, 1048576L, 1048576L, x, gamma, b_out);
    } else {
        // ---- fallback: previous verified path (23,724,032 B of ws) ----
        unsigned short* kbuf = (unsigned short*)d_out;
        unsigned short* Gp  = (unsigned short*)(ws);                  // 16,777,216
        unsigned short* G   = (unsigned short*)(ws + 16777216);       //  2,097,152
        unsigned short* W2  = (unsigned short*)(ws + 18874368);       //  2,097,152
        unsigned short* W3  = (unsigned short*)(ws + 20971520);       //  2,097,152
        unsigned short* WqT = (unsigned short*)(ws + 23068672);       //    131,072
        unsigned short* wb  = (unsigned short*)(ws + 23199744);       //    393,216
        unsigned short* wob = (unsigned short*)(ws + 23592960);       //    131,072

        k_cvt<<<dim3(96), 256, 0, stream>>>(w_qkv, wb, 24576);
        k_cvt<<<dim3(32), 256, 0, stream>>>(w_out, wob, 8192);
        k_transpose<<<dim3(1, 32, 1), 256, 0, stream>>>(wb, WqT, 256, 256);

        gemm_bn<0><<<dim3(32, 2, 16), 256, 0, stream>>>(
            wb + 65536, x, kbuf, 256, 256, 4096, 4096,
            0L, 1048576L, 1048576L, nullptr, nullptr, nullptr);

        k_softmax<<<dim3(4096), 256, 0, stream>>>(kbuf);

        gemm_bt<1, 0><<<dim3(2, 2, 128), 256, 0, stream>>>(
            kbuf, x, Gp, 512, 512, 4096, 4096, 256,
            1048576L, 1048576L, 65536L, nullptr, nullptr, nullptr);

        k_gred<<<dim3(512), 256, 0, stream>>>(Gp, G);
        k_ctxw2<<<dim3(4, 16), 256, 0, stream>>>(G, wb, wob, W2);

        gemm_bt<0, 0><<<dim3(2, 2, 16), 256, 0, stream>>>(
            W2, WqT, W3, 256, 0, 256, 256, 256,
            65536L, 0L, 65536L, nullptr, nullptr, nullptr);

        gemm_bn<1><<<dim3(32, 2, 16), 256, 0, stream>>>(
            W3, x, d_out, 256, 256, 4096, 4096,
            65536L, 1048576L, 1048576L, x, gamma, b_out);
    }
}

// Round 3
// 229.989 us; speedup vs baseline: 1.0092x; 1.0092x over previous
//
#include <hip/hip_runtime.h>
#include <stdint.h>

typedef short s16x8 __attribute__((ext_vector_type(8)));
typedef float f32x4 __attribute__((ext_vector_type(4)));
typedef unsigned int u32x2 __attribute__((ext_vector_type(2)));

typedef const __attribute__((address_space(1))) void glb_cv;
typedef __attribute__((address_space(3))) void lds_v;

__device__ __forceinline__ float bits2f(unsigned short u) {
    union { unsigned int i; float f; } c; c.i = ((unsigned int)u) << 16; return c.f;
}
__device__ __forceinline__ unsigned short f2bits(float f) {
    union { float f; unsigned int i; } c; c.f = f;
    unsigned int x = c.i;
    unsigned int r = (x + 0x7FFFu + ((x >> 16) & 1u)) >> 16;
    return (unsigned short)r;
}
__device__ __forceinline__ unsigned int pack2(float a, float b) {
    return (unsigned int)f2bits(a) | ((unsigned int)f2bits(b) << 16);
}

// async global->LDS, 16B per lane. LDS dest = wave-uniform base + lane*16.
__device__ __forceinline__ void gl_lds16(const void* g, void* l) {
    __builtin_amdgcn_global_load_lds((glb_cv*)g, (lds_v*)l, 16, 0, 0);
}

// ---------------------------------------------------------------------------
// f32 -> bf16 bulk convert; n8 = n/8  (fallback path only)
__global__ __launch_bounds__(256) void k_cvt(
    const float* __restrict__ src, unsigned short* __restrict__ dst, int n8)
{
    int i = blockIdx.x * 256 + threadIdx.x;
    if (i >= n8) return;
    const float* s = src + (size_t)i * 8;
    float4 a = *(const float4*)s, b = *(const float4*)(s + 4);
    unsigned int q[4] = { pack2(a.x, a.y), pack2(a.z, a.w), pack2(b.x, b.y), pack2(b.z, b.w) };
    *(s16x8*)(dst + (size_t)i * 8) = *(s16x8*)q;
}

// ---------------------------------------------------------------------------
// transpose (WqT only, 256x256 bf16): dst[dr][c] = src[c][dr]  (fallback only)
__global__ __launch_bounds__(256) void k_transpose(
    const unsigned short* __restrict__ src, unsigned short* __restrict__ dst,
    int RS, int DS)
{
    int dr = blockIdx.x * 256 + threadIdx.x;
    int c0 = blockIdx.y * 8;
    __align__(16) unsigned short tmp[8];
#pragma unroll
    for (int j = 0; j < 8; ++j) tmp[j] = src[(size_t)(c0 + j) * RS + dr];
    *(s16x8*)(dst + (size_t)dr * DS + c0) = *(s16x8*)tmp;
}

// ---------------------------------------------------------------------------
// merged weight prep: wb = bf16(w_qkv) [768x256]; wob = bf16(w_out) [256x256];
// WqT[c][hd] = bf16(w_qkv[hd][c]) for hd<256. grid 160 blocks x 256.
__global__ __launch_bounds__(256) void k_prepw(
    const float* __restrict__ wqkv, const float* __restrict__ wout,
    unsigned short* __restrict__ wb, unsigned short* __restrict__ wob,
    unsigned short* __restrict__ WqT)
{
    int i = blockIdx.x * 256 + threadIdx.x;
    if (i < 32768) {
        const float* s; unsigned short* d; int j;
        if (i < 24576) { s = wqkv; d = wb; j = i; }
        else           { s = wout; d = wob; j = i - 24576; }
        const float* sp = s + (size_t)j * 8;
        float4 a = *(const float4*)sp, b = *(const float4*)(sp + 4);
        unsigned int q[4] = { pack2(a.x, a.y), pack2(a.z, a.w), pack2(b.x, b.y), pack2(b.z, b.w) };
        *(s16x8*)(d + (size_t)j * 8) = *(s16x8*)q;
    } else {
        int j = i - 32768;                 // [0, 8192)
        int dr = j & 255, c0 = (j >> 8) * 8;
        __align__(16) unsigned short tmp[8];
#pragma unroll
        for (int jj = 0; jj < 8; ++jj)
            tmp[jj] = f2bits(wqkv[(size_t)(c0 + jj) * 256 + dr]);
        *(s16x8*)(WqT + (size_t)dr * 256 + c0) = *(s16x8*)tmp;
    }
}

// ---------------------------------------------------------------------------
// x [b][256 c][4096 n] f32  ->  xT [b][4096 n][256 c] bf16  AND
//                               xbf [b][256 c][4096 n] bf16 (same rounding)
__global__ __launch_bounds__(256) void k_prep(
    const float* __restrict__ x, unsigned short* __restrict__ xT,
    unsigned short* __restrict__ xbf)
{
    __shared__ unsigned short Ts[64][264];
    int b = blockIdx.y, n0 = blockIdx.x * 64, t = threadIdx.x;
    const float* xb = x + (size_t)b * 1048576;
    unsigned short* xbfb = xbf + (size_t)b * 1048576;
#pragma unroll
    for (int i = 0; i < 16; ++i) {
        int idx = t + i * 256;               // 0..4095
        int c = idx >> 4, nq = idx & 15;
        float4 v = *(const float4*)(xb + (size_t)c * 4096 + n0 + nq * 4);
        u32x2 q; q[0] = pack2(v.x, v.y); q[1] = pack2(v.z, v.w);
        *(u32x2*)(xbfb + (size_t)c * 4096 + n0 + nq * 4) = q;
        float vv[4] = { v.x, v.y, v.z, v.w };
#pragma unroll
        for (int e = 0; e < 4; ++e) {
            int ee = (e + c) & 3;            // rotate store order: spread LDS banks
            Ts[nq * 4 + ee][c] = f2bits(vv[ee]);
        }
    }
    __syncthreads();
    unsigned short* xTb = xT + (size_t)b * 1048576 + (size_t)n0 * 256;
#pragma unroll
    for (int i = 0; i < 8; ++i) {
        int idx = t + i * 256;               // 0..2047
        int nl = idx >> 5, cg = (idx & 31) * 8;
        *(s16x8*)(xTb + (size_t)nl * 256 + cg) = *(const s16x8*)&Ts[nl][cg];
    }
}

// ---------------------------------------------------------------------------
// gemm_bt2: C[m][n] = sum_k A[m][k] * Bt[n][k]; all bf16 operands.
// BM=BN=128, BK=64, block=256. global_load_lds staging, linear LDS +
// XOR chunk swizzle (slot c of row r holds source chunk c^(r&7); involution,
// applied on BOTH stage-source and read side -> conflict-free b128 reads).
// EPI==0: C bf16.  EPI==1: C f32, C = gamma[m]*(acc+bias[m]) + Xres[m][n].
template <int EPI>
__global__ __launch_bounds__(256) void gemm_bt2(
    const unsigned short* __restrict__ A, const unsigned short* __restrict__ Bt,
    void* __restrict__ C,
    int K, int Kstep, int lda, int ldb, int ldc,
    long Abs, long Bbs, long Cbs,
    const float* __restrict__ Xres,
    const float* __restrict__ gamma,
    const float* __restrict__ bias)
{
    __shared__ __align__(16) unsigned short As[128 * 64];
    __shared__ __align__(16) unsigned short Bs[128 * 64];
    int bz = blockIdx.z;
    int b = bz & 15, kc = bz >> 4;
    int m0 = blockIdx.y * 128, n0 = blockIdx.x * 128;
    const unsigned short* Ab = A + (size_t)b * Abs + (size_t)m0 * lda + (size_t)kc * Kstep;
    const unsigned short* Bb = Bt + (size_t)b * Bbs + (size_t)n0 * ldb + (size_t)kc * Kstep;
    int t = threadIdx.x;
    int w = t >> 6, l = t & 63, lm = l & 15, lq = l >> 4;
    int mw = (w >> 1) * 64, nw = (w & 1) * 64;

    f32x4 acc[4][4];
    f32x4 zero = {0.f, 0.f, 0.f, 0.f};
#pragma unroll
    for (int i = 0; i < 4; ++i)
#pragma unroll
        for (int j = 0; j < 4; ++j) acc[i][j] = zero;

    for (int kk = 0; kk < K; kk += 64) {
#pragma unroll
        for (int i = 0; i < 4; ++i) {
            int idx = t + i * 256;           // slot index; r=idx>>3, c=idx&7
            int r = idx >> 3;
            int sch = (idx & 7) ^ (r & 7);   // source chunk for this slot
            int lbase = (i * 256 + w * 64) * 8;  // wave-uniform LDS elem offset
            gl_lds16(Ab + (size_t)r * lda + kk + sch * 8, &As[lbase]);
            gl_lds16(Bb + (size_t)r * ldb + kk + sch * 8, &Bs[lbase]);
        }
        __syncthreads();                     // drains vmcnt + barrier
#pragma unroll
        for (int ks = 0; ks < 2; ++ks) {
            s16x8 af[4], bfr[4];
#pragma unroll
            for (int mi = 0; mi < 4; ++mi) {
                int row = mw + mi * 16 + lm;
                af[mi] = *(const s16x8*)&As[row * 64 + (((ks * 4 + lq) ^ (row & 7)) << 3)];
            }
#pragma unroll
            for (int ni = 0; ni < 4; ++ni) {
                int row = nw + ni * 16 + lm;
                bfr[ni] = *(const s16x8*)&Bs[row * 64 + (((ks * 4 + lq) ^ (row & 7)) << 3)];
            }
#pragma unroll
            for (int mi = 0; mi < 4; ++mi)
#pragma unroll
                for (int ni = 0; ni < 4; ++ni)
                    acc[mi][ni] = __builtin_amdgcn_mfma_f32_16x16x32_bf16(af[mi], bfr[ni], acc[mi][ni], 0, 0, 0);
        }
        __syncthreads();
    }

    if (EPI == 0) {
        unsigned short* Cb = (unsigned short*)C + (size_t)bz * Cbs;
#pragma unroll
        for (int mi = 0; mi < 4; ++mi)
#pragma unroll
            for (int r = 0; r < 4; ++r) {
                int m = m0 + mw + mi * 16 + lq * 4 + r;
#pragma unroll
                for (int ni = 0; ni < 4; ++ni) {
                    int n = n0 + nw + ni * 16 + lm;
                    Cb[(size_t)m * ldc + n] = f2bits(acc[mi][ni][r]);
                }
            }
    } else {
        float* Cb = (float*)C + (size_t)bz * Cbs;
        const float* Xb = Xres + (size_t)bz * Cbs;
#pragma unroll
        for (int mi = 0; mi < 4; ++mi)
#pragma unroll
            for (int r = 0; r < 4; ++r) {
                int m = m0 + mw + mi * 16 + lq * 4 + r;
                float g = gamma[m], bo = bias[m];
#pragma unroll
                for (int ni = 0; ni < 4; ++ni) {
                    int n = n0 + nw + ni * 16 + lm;
                    size_t idx = (size_t)m * ldc + n;
                    Cb[idx] = g * (acc[mi][ni][r] + bo) + Xb[idx];
                }
            }
    }
}

// ---------------------------------------------------------------------------
// gemm64: 64x64-tile variant of gemm_bt2 (bf16 out). Used by KG and W3.
__global__ __launch_bounds__(256) void gemm64(
    const unsigned short* __restrict__ A, const unsigned short* __restrict__ Bt,
    unsigned short* __restrict__ C,
    int K, int Kstep, int lda, int ldb, int ldc,
    long Abs, long Bbs, long Cbs)
{
    __shared__ __align__(16) unsigned short As[64 * 64];
    __shared__ __align__(16) unsigned short Bs[64 * 64];
    int bz = blockIdx.z;
    int b = bz & 15, kc = bz >> 4;
    int m0 = blockIdx.y * 64, n0 = blockIdx.x * 64;
    const unsigned short* Ab = A + (size_t)b * Abs + (size_t)m0 * lda + (size_t)kc * Kstep;
    const unsigned short* Bb = Bt + (size_t)b * Bbs + (size_t)n0 * ldb + (size_t)kc * Kstep;
    int t = threadIdx.x;
    int w = t >> 6, l = t & 63, lm = l & 15, lq = l >> 4;
    int mw = (w >> 1) * 32, nw = (w & 1) * 32;

    f32x4 acc[2][2];
    f32x4 zero = {0.f, 0.f, 0.f, 0.f};
#pragma unroll
    for (int i = 0; i < 2; ++i)
#pragma unroll
        for (int j = 0; j < 2; ++j) acc[i][j] = zero;

    for (int kk = 0; kk < K; kk += 64) {
#pragma unroll
        for (int i = 0; i < 2; ++i) {
            int idx = t + i * 256;           // 0..511
            int r = idx >> 3;
            int sch = (idx & 7) ^ (r & 7);
            int lbase = (i * 256 + w * 64) * 8;
            gl_lds16(Ab + (size_t)r * lda + kk + sch * 8, &As[lbase]);
            gl_lds16(Bb + (size_t)r * ldb + kk + sch * 8, &Bs[lbase]);
        }
        __syncthreads();
#pragma unroll
        for (int ks = 0; ks < 2; ++ks) {
            s16x8 af[2], bfr[2];
#pragma unroll
            for (int mi = 0; mi < 2; ++mi) {
                int row = mw + mi * 16 + lm;
                af[mi] = *(const s16x8*)&As[row * 64 + (((ks * 4 + lq) ^ (row & 7)) << 3)];
            }
#pragma unroll
            for (int ni = 0; ni < 2; ++ni) {
                int row = nw + ni * 16 + lm;
                bfr[ni] = *(const s16x8*)&Bs[row * 64 + (((ks * 4 + lq) ^ (row & 7)) << 3)];
            }
#pragma unroll
            for (int mi = 0; mi < 2; ++mi)
#pragma unroll
                for (int ni = 0; ni < 2; ++ni)
                    acc[mi][ni] = __builtin_amdgcn_mfma_f32_16x16x32_bf16(af[mi], bfr[ni], acc[mi][ni], 0, 0, 0);
        }
        __syncthreads();
    }

    unsigned short* Cb = C + (size_t)bz * Cbs;
#pragma unroll
    for (int mi = 0; mi < 2; ++mi)
#pragma unroll
        for (int r = 0; r < 4; ++r) {
            int m = m0 + mw + mi * 16 + lq * 4 + r;
#pragma unroll
            for (int ni = 0; ni < 2; ++ni) {
                int n = n0 + nw + ni * 16 + lm;
                Cb[(size_t)m * ldc + n] = f2bits(acc[mi][ni][r]);
            }
        }
}

// ---------------------------------------------------------------------------
// gemm_bt (fallback path only): reg-staged, padded LDS, optional f32 B.
template <int BF32, int EPI>
__global__ __launch_bounds__(256) void gemm_bt(
    const unsigned short* __restrict__ A, const void* __restrict__ Bt,
    void* __restrict__ C,
    int K, int Kstep, int lda, int ldb, int ldc,
    long Abs, long Bbs, long Cbs,
    const float* __restrict__ Xres,
    const float* __restrict__ gamma,
    const float* __restrict__ bias)
{
    __shared__ unsigned short As[128][72];
    __shared__ unsigned short Bs[128][72];
    int bz = blockIdx.z;
    int b = bz & 15, kc = bz >> 4;
    int m0 = blockIdx.y * 128, n0 = blockIdx.x * 128;
    const unsigned short* Ab = A + (size_t)b * Abs + (size_t)m0 * lda + (size_t)kc * Kstep;
    size_t boff = (size_t)b * Bbs + (size_t)n0 * ldb + (size_t)kc * Kstep;
    int t = threadIdx.x;
    int w = t >> 6, l = t & 63, lm = l & 15, lq = l >> 4;
    int mw = (w >> 1) * 64, nw = (w & 1) * 64;

    f32x4 acc[4][4];
    f32x4 zero = {0.f, 0.f, 0.f, 0.f};
#pragma unroll
    for (int i = 0; i < 4; ++i)
#pragma unroll
        for (int j = 0; j < 4; ++j) acc[i][j] = zero;

    for (int kk = 0; kk < K; kk += 64) {
#pragma unroll
        for (int i = 0; i < 4; ++i) {
            int idx = t + i * 256;
            int r = idx >> 3, ch = idx & 7;
            *(s16x8*)&As[r][ch * 8] = *(const s16x8*)(Ab + (size_t)r * lda + kk + ch * 8);
            if (BF32) {
                const float* bp = (const float*)Bt + boff + (size_t)r * ldb + kk + ch * 8;
                float4 v0 = *(const float4*)bp, v1 = *(const float4*)(bp + 4);
                unsigned int q[4] = { pack2(v0.x, v0.y), pack2(v0.z, v0.w),
                                      pack2(v1.x, v1.y), pack2(v1.z, v1.w) };
                *(s16x8*)&Bs[r][ch * 8] = *(s16x8*)q;
            } else {
                const unsigned short* bp = (const unsigned short*)Bt + boff + (size_t)r * ldb + kk + ch * 8;
                *(s16x8*)&Bs[r][ch * 8] = *(const s16x8*)bp;
            }
        }
        __syncthreads();
#pragma unroll
        for (int ks = 0; ks < 2; ++ks) {
            s16x8 af[4], bfr[4];
#pragma unroll
            for (int mi = 0; mi < 4; ++mi) af[mi]  = *(const s16x8*)&As[mw + mi * 16 + lm][ks * 32 + lq * 8];
#pragma unroll
            for (int ni = 0; ni < 4; ++ni) bfr[ni] = *(const s16x8*)&Bs[nw + ni * 16 + lm][ks * 32 + lq * 8];
#pragma unroll
            for (int mi = 0; mi < 4; ++mi)
#pragma unroll
                for (int ni = 0; ni < 4; ++ni)
                    acc[mi][ni] = __builtin_amdgcn_mfma_f32_16x16x32_bf16(af[mi], bfr[ni], acc[mi][ni], 0, 0, 0);
        }
        __syncthreads();
    }

    if (EPI == 0) {
        unsigned short* Cb = (unsigned short*)C + (size_t)bz * Cbs;
#pragma unroll
        for (int mi = 0; mi < 4; ++mi)
#pragma unroll
            for (int r = 0; r < 4; ++r) {
                int m = m0 + mw + mi * 16 + lq * 4 + r;
#pragma unroll
                for (int ni = 0; ni < 4; ++ni) {
                    int n = n0 + nw + ni * 16 + lm;
                    Cb[(size_t)m * ldc + n] = f2bits(acc[mi][ni][r]);
                }
            }
    } else {
        float* Cb = (float*)C + (size_t)bz * Cbs;
        const float* Xb = Xres + (size_t)bz * Cbs;
#pragma unroll
        for (int mi = 0; mi < 4; ++mi)
#pragma unroll
            for (int r = 0; r < 4; ++r) {
                int m = m0 + mw + mi * 16 + lq * 4 + r;
                float g = gamma[m], bo = bias[m];
#pragma unroll
                for (int ni = 0; ni < 4; ++ni) {
                    int n = n0 + nw + ni * 16 + lm;
                    size_t idx = (size_t)m * ldc + n;
                    Cb[idx] = g * (acc[mi][ni][r] + bo) + Xb[idx];
                }
            }
    }
}

// ---------------------------------------------------------------------------
// gemm_bn (fallback path only): C[m][n] = sum_k A[m][k] * B[k][n]
template <int EPI>
__global__ __launch_bounds__(256) void gemm_bn(
    const unsigned short* __restrict__ A, const float* __restrict__ B,
    void* __restrict__ C,
    int K, int lda, int ldb, int ldc,
    long Abs, long Bbs, long Cbs,
    const float* __restrict__ Xres,
    const float* __restrict__ gamma,
    const float* __restrict__ bias)
{
    __shared__ unsigned short As[128][72];
    __shared__ unsigned short Bs[64][130];
    int bz = blockIdx.z;
    int m0 = blockIdx.y * 128, n0 = blockIdx.x * 128;
    const unsigned short* Ab = A + (size_t)bz * Abs + (size_t)m0 * lda;
    const float* Bb = B + (size_t)bz * Bbs + n0;
    int t = threadIdx.x;
    int w = t >> 6, l = t & 63, lm = l & 15, lq = l >> 4;
    int mw = (w >> 1) * 64, nw = (w & 1) * 64;

    f32x4 acc[4][4];
    f32x4 zero = {0.f, 0.f, 0.f, 0.f};
#pragma unroll
    for (int i = 0; i < 4; ++i)
#pragma unroll
        for (int j = 0; j < 4; ++j) acc[i][j] = zero;

    for (int kk = 0; kk < K; kk += 64) {
#pragma unroll
        for (int i = 0; i < 4; ++i) {
            int idx = t + i * 256;
            int r = idx >> 3, ch = idx & 7;
            *(s16x8*)&As[r][ch * 8] = *(const s16x8*)(Ab + (size_t)r * lda + kk + ch * 8);
        }
#pragma unroll
        for (int i = 0; i < 4; ++i) {
            int idx = t + i * 256;
            int c = idx >> 4, cc = idx & 15;
            const float* bp = Bb + (size_t)(kk + c) * ldb + cc * 8;
            float4 v0 = *(const float4*)bp, v1 = *(const float4*)(bp + 4);
            unsigned int* q = (unsigned int*)&Bs[c][cc * 8];
            q[0] = pack2(v0.x, v0.y); q[1] = pack2(v0.z, v0.w);
            q[2] = pack2(v1.x, v1.y); q[3] = pack2(v1.z, v1.w);
        }
        __syncthreads();
#pragma unroll
        for (int ks = 0; ks < 2; ++ks) {
            s16x8 af[4];
#pragma unroll
            for (int mi = 0; mi < 4; ++mi) af[mi] = *(const s16x8*)&As[mw + mi * 16 + lm][ks * 32 + lq * 8];
#pragma unroll
            for (int ni = 0; ni < 4; ++ni) {
                s16x8 bfr;
#pragma unroll
                for (int j = 0; j < 8; ++j) bfr[j] = (short)Bs[ks * 32 + lq * 8 + j][nw + ni * 16 + lm];
#pragma unroll
                for (int mi = 0; mi < 4; ++mi)
                    acc[mi][ni] = __builtin_amdgcn_mfma_f32_16x16x32_bf16(af[mi], bfr, acc[mi][ni], 0, 0, 0);
            }
        }
        __syncthreads();
    }

#pragma unroll
    for (int mi = 0; mi < 4; ++mi)
#pragma unroll
        for (int r = 0; r < 4; ++r) {
            int m = m0 + mw + mi * 16 + lq * 4 + r;
            float g = 0.f, bo = 0.f;
            if (EPI == 1) { g = gamma[m]; bo = bias[m]; }
#pragma unroll
            for (int ni = 0; ni < 4; ++ni) {
                int n = n0 + nw + ni * 16 + lm;
                size_t idx = (size_t)m * ldc + n;
                float v = acc[mi][ni][r];
                if (EPI == 1) {
                    float* Cb = (float*)C + (size_t)bz * Cbs;
                    Cb[idx] = g * (v + bo) + Xres[(size_t)bz * Cbs + idx];
                } else {
                    unsigned short* Cb = (unsigned short*)C + (size_t)bz * Cbs;
                    Cb[idx] = f2bits(v);
                }
            }
        }
}

// ---------------------------------------------------------------------------
// softmax over n (4096) for each of 4096 rows of kbuf (bf16)
__global__ __launch_bounds__(256) void k_softmax(unsigned short* __restrict__ kbuf)
{
    unsigned short* p = kbuf + (size_t)blockIdx.x * 4096;
    int t = threadIdx.x;
    __shared__ float red[4];

    s16x8 r0 = *(const s16x8*)(p + t * 16);
    s16x8 r1 = *(const s16x8*)(p + t * 16 + 8);
    float v[16];
    float m = -1e30f;
#pragma unroll
    for (int i = 0; i < 8; ++i) { v[i] = bits2f((unsigned short)r0[i]); v[8 + i] = bits2f((unsigned short)r1[i]); }
#pragma unroll
    for (int i = 0; i < 16; ++i) m = fmaxf(m, v[i]);
#pragma unroll
    for (int off = 32; off >= 1; off >>= 1) m = fmaxf(m, __shfl_xor(m, off));
    if ((t & 63) == 0) red[t >> 6] = m;
    __syncthreads();
    m = fmaxf(fmaxf(red[0], red[1]), fmaxf(red[2], red[3]));
    __syncthreads();

    float s = 0.f;
#pragma unroll
    for (int i = 0; i < 16; ++i) { v[i] = __expf(v[i] - m); s += v[i]; }
#pragma unroll
    for (int off = 32; off >= 1; off >>= 1) s += __shfl_xor(s, off);
    if ((t & 63) == 0) red[t >> 6] = s;
    __syncthreads();
    s = red[0] + red[1] + red[2] + red[3];
    float inv = 1.0f / s;

    __align__(16) unsigned short otmp[16];
#pragma unroll
    for (int i = 0; i < 16; ++i) otmp[i] = f2bits(v[i] * inv);
    *(s16x8*)(p + t * 16) = *(s16x8*)(otmp);
    *(s16x8*)(p + t * 16 + 8) = *(s16x8*)(otmp + 8);
}

// ---------------------------------------------------------------------------
// G[b][i] = sum_{kc<NC} Gp[kc*16+b][i]
template <int NC>
__global__ __launch_bounds__(256) void k_gred(
    const unsigned short* __restrict__ Gp, unsigned short* __restrict__ G)
{
    int gid = blockIdx.x * 256 + threadIdx.x;   // [0, 131072)
    int b = gid >> 13;
    size_t i8 = (size_t)(gid & 8191) * 8;
    float s[8] = {0.f, 0.f, 0.f, 0.f, 0.f, 0.f, 0.f, 0.f};
#pragma unroll
    for (int kc = 0; kc < NC; ++kc) {
        s16x8 v = *(const s16x8*)(Gp + (size_t)(kc * 16 + b) * 65536 + i8);
#pragma unroll
        for (int j = 0; j < 8; ++j) s[j] += bits2f((unsigned short)v[j]);
    }
    __align__(16) unsigned short tmp[8];
#pragma unroll
    for (int j = 0; j < 8; ++j) tmp[j] = f2bits(s[j]);
    *(s16x8*)(G + (size_t)b * 65536 + i8) = *(s16x8*)tmp;
}

// ---------------------------------------------------------------------------
// per (b,h): ctx[d][e] = sum_c G[b][h*64+d][c] * Wv[h*64+e][c]  (K=256)
// then      W2[b][o][h*64+d] = sum_e w_out[o][h*64+e] * ctx[d][e] (K=64)
__global__ __launch_bounds__(256) void k_ctxw2(
    const unsigned short* __restrict__ G, const unsigned short* __restrict__ wb,
    const unsigned short* __restrict__ wob, unsigned short* __restrict__ W2)
{
    __shared__ unsigned short ctxs[64][72];
    int h = blockIdx.x, b = blockIdx.y;
    int t = threadIdx.x, w = t >> 6, l = t & 63, lm = l & 15, lq = l >> 4;
    const unsigned short* Gb = G + (size_t)b * 65536 + (size_t)(h * 64) * 256;
    const unsigned short* Wv = wb + 131072 + (size_t)(h * 64) * 256;
    f32x4 zero = {0.f, 0.f, 0.f, 0.f};

    f32x4 acc[4];
#pragma unroll
    for (int i = 0; i < 4; ++i) acc[i] = zero;
    for (int kk = 0; kk < 256; kk += 32) {
        s16x8 a = *(const s16x8*)(Gb + (size_t)(w * 16 + lm) * 256 + kk + lq * 8);
#pragma unroll
        for (int ni = 0; ni < 4; ++ni) {
            s16x8 bb = *(const s16x8*)(Wv + (size_t)(ni * 16 + lm) * 256 + kk + lq * 8);
            acc[ni] = __builtin_amdgcn_mfma_f32_16x16x32_bf16(a, bb, acc[ni], 0, 0, 0);
        }
    }
#pragma unroll
    for (int ni = 0; ni < 4; ++ni)
#pragma unroll
        for (int r = 0; r < 4; ++r)
            ctxs[w * 16 + lq * 4 + r][ni * 16 + lm] = f2bits(acc[ni][r]);
    __syncthreads();

    f32x4 acc2[4][4];
#pragma unroll
    for (int i = 0; i < 4; ++i)
#pragma unroll
        for (int j = 0; j < 4; ++j) acc2[i][j] = zero;
#pragma unroll
    for (int ks = 0; ks < 2; ++ks) {
        s16x8 af[4], bfr[4];
#pragma unroll
        for (int mi = 0; mi < 4; ++mi)
            af[mi] = *(const s16x8*)(wob + (size_t)(w * 64 + mi * 16 + lm) * 256 + h * 64 + ks * 32 + lq * 8);
#pragma unroll
        for (int ni = 0; ni < 4; ++ni) bfr[ni] = *(const s16x8*)&ctxs[ni * 16 + lm][ks * 32 + lq * 8];
#pragma unroll
        for (int mi = 0; mi < 4; ++mi)
#pragma unroll
            for (int ni = 0; ni < 4; ++ni)
                acc2[mi][ni] = __builtin_amdgcn_mfma_f32_16x16x32_bf16(af[mi], bfr[ni], acc2[mi][ni], 0, 0, 0);
    }
    unsigned short* W2b = W2 + (size_t)b * 65536;
#pragma unroll
    for (int mi = 0; mi < 4; ++mi)
#pragma unroll
        for (int r = 0; r < 4; ++r) {
            int o = w * 64 + mi * 16 + lq * 4 + r;
#pragma unroll
            for (int ni = 0; ni < 4; ++ni)
                W2b[(size_t)o * 256 + h * 64 + ni * 16 + lm] = f2bits(acc2[mi][ni][r]);
        }
}

// ---------------------------------------------------------------------------
extern "C" void kernel_launch(void* const* d_in, const int* in_sizes, int n_in,
                              void* d_out, int out_size, void* d_ws, size_t ws_size,
                              hipStream_t stream)
{
    (void)in_sizes; (void)n_in; (void)out_size;
    const float* x      = (const float*)d_in[0]; // [16][256][4096] f32
    const float* w_qkv  = (const float*)d_in[1]; // [768][256] f32
    const float* w_out  = (const float*)d_in[2]; // [256][256] f32
    const float* b_out  = (const float*)d_in[3]; // [256] f32
    const float* gamma  = (const float*)d_in[4]; // [256] f32

    char* ws = (char*)d_ws;
    const size_t NEED = 40501248;

    if (ws_size >= NEED) {
        // ws layout (40,501,248 B total — same NEED as verified round 1):
        unsigned short* xT  = (unsigned short*)ws;                    // [16][4096][256] bf16 = 33,554,432
        unsigned short* W3  = (unsigned short*)(ws + 33554432);       //  2,097,152
        unsigned short* Gp  = (unsigned short*)(ws + 35651584);       //  4,194,304 (kc=2 split)
        unsigned short* WqT = (unsigned short*)(ws + 39845888);       //    131,072
        unsigned short* wb  = (unsigned short*)(ws + 39976960);       //    393,216
        unsigned short* wob = (unsigned short*)(ws + 40370176);       //    131,072
        // d_out (64MB) as scratch until K5 rewrites it:
        unsigned short* kbuf = (unsigned short*)d_out;                // [0, 32MB) — dead after KG
        unsigned short* xbf  = (unsigned short*)d_out + 16777216;     // [32MB, 64MB) — dead after KG
        unsigned short* G    = (unsigned short*)d_out;                // overlays dead kbuf (2MB)
        unsigned short* W2   = (unsigned short*)d_out + 1048576;      // +2MB (2MB) — dead before K5

        // weights: wb/wob bf16 + WqT
        k_prepw<<<dim3(160), 256, 0, stream>>>(w_qkv, w_out, wb, wob, WqT);

        // xT = transpose(x) bf16; xbf = x bf16 (same layout)
        k_prep<<<dim3(64, 16), 256, 0, stream>>>(x, xT, xbf);

        // K1: k = Wk @ x  == gemm_bt2(A=Wk, Bt=xT)   (M=256,N=4096,K=256)
        gemm_bt2<0><<<dim3(32, 2, 16), 256, 0, stream>>>(
            wb + 65536, xT, kbuf, 256, 0, 256, 256, 4096,
            0L, 1048576L, 1048576L, nullptr, nullptr, nullptr);

        // K2: softmax rows of k
        k_softmax<<<dim3(4096), 256, 0, stream>>>(kbuf);

        // KG: Gp[kc*16+b] = softk_b[:,chunk] @ xbf_b[:,chunk]^T (K-split x2, 64² tiles)
        gemm64<<<dim3(4, 4, 32), 256, 0, stream>>>(
            kbuf, xbf, Gp, 2048, 2048, 4096, 4096, 256,
            1048576L, 1048576L, 65536L);

        // G = sum_kc Gp  (G overlays dead kbuf region)
        k_gred<2><<<dim3(512), 256, 0, stream>>>(Gp, G);

        // ctx + W2 fused per (b,h)
        k_ctxw2<<<dim3(4, 16), 256, 0, stream>>>(G, wb, wob, W2);

        // W3[b] = W2[b] @ Wq
        gemm64<<<dim3(4, 4, 16), 256, 0, stream>>>(
            W2, WqT, W3, 256, 0, 256, 256, 256,
            65536L, 0L, 65536L);

        // K5: out(f32) = gamma*(W3 @ x + b_out) + x  == gemm_bt2<1>(A=W3, Bt=xT)
        gemm_bt2<1><<<dim3(32, 2, 16), 256, 0, stream>>>(
            W3, xT, d_out, 256, 0, 256, 256, 4096,
            65536L, 1048576L, 1048576L, x, gamma, b_out);
    } else {
        // ---- fallback: previously verified path (23,724,032 B of ws) ----
        unsigned short* kbuf = (unsigned short*)d_out;
        unsigned short* Gp  = (unsigned short*)(ws);                  // 16,777,216
        unsigned short* G   = (unsigned short*)(ws + 16777216);       //  2,097,152
        unsigned short* W2  = (unsigned short*)(ws + 18874368);       //  2,097,152
        unsigned short* W3  = (unsigned short*)(ws + 20971520);       //  2,097,152
        unsigned short* WqT = (unsigned short*)(ws + 23068672);       //    131,072
        unsigned short* wb  = (unsigned short*)(ws + 23199744);       //    393,216
        unsigned short* wob = (unsigned short*)(ws + 23592960);       //    131,072

        k_cvt<<<dim3(96), 256, 0, stream>>>(w_qkv, wb, 24576);
        k_cvt<<<dim3(32), 256, 0, stream>>>(w_out, wob, 8192);
        k_transpose<<<dim3(1, 32, 1), 256, 0, stream>>>(wb, WqT, 256, 256);

        gemm_bn<0><<<dim3(32, 2, 16), 256, 0, stream>>>(
            wb + 65536, x, kbuf, 256, 256, 4096, 4096,
            0L, 1048576L, 1048576L, nullptr, nullptr, nullptr);

        k_softmax<<<dim3(4096), 256, 0, stream>>>(kbuf);

        gemm_bt<1, 0><<<dim3(2, 2, 128), 256, 0, stream>>>(
            kbuf, x, Gp, 512, 512, 4096, 4096, 256,
            1048576L, 1048576L, 65536L, nullptr, nullptr, nullptr);

        k_gred<8><<<dim3(512), 256, 0, stream>>>(Gp, G);
        k_ctxw2<<<dim3(4, 16), 256, 0, stream>>>(G, wb, wob, W2);

        gemm_bt<0, 0><<<dim3(2, 2, 16), 256, 0, stream>>>(
            W2, WqT, W3, 256, 0, 256, 256, 256,
            65536L, 0L, 65536L, nullptr, nullptr, nullptr);

        gemm_bn<1><<<dim3(32, 2, 16), 256, 0, stream>>>(
            W3, x, d_out, 256, 256, 4096, 4096,
            65536L, 1048576L, 1048576L, x, gamma, b_out);
    }
}

// Round 4
// 229.453 us; speedup vs baseline: 1.0115x; 1.0023x over previous
//
#include <hip/hip_runtime.h>
#include <stdint.h>

typedef short s16x8 __attribute__((ext_vector_type(8)));
typedef float f32x4 __attribute__((ext_vector_type(4)));
typedef unsigned int u32x2 __attribute__((ext_vector_type(2)));

typedef const __attribute__((address_space(1))) void glb_cv;
typedef __attribute__((address_space(3))) void lds_v;

__device__ __forceinline__ float bits2f(unsigned short u) {
    union { unsigned int i; float f; } c; c.i = ((unsigned int)u) << 16; return c.f;
}
__device__ __forceinline__ unsigned short f2bits(float f) {
    union { float f; unsigned int i; } c; c.f = f;
    unsigned int x = c.i;
    unsigned int r = (x + 0x7FFFu + ((x >> 16) & 1u)) >> 16;
    return (unsigned short)r;
}
__device__ __forceinline__ unsigned int pack2(float a, float b) {
    return (unsigned int)f2bits(a) | ((unsigned int)f2bits(b) << 16);
}

// async global->LDS, 16B per lane. LDS dest = wave-uniform base + lane*16.
__device__ __forceinline__ void gl_lds16(const void* g, void* l) {
    __builtin_amdgcn_global_load_lds((glb_cv*)g, (lds_v*)l, 16, 0, 0);
}

// ---------------------------------------------------------------------------
// f32 -> bf16 bulk convert; n8 = n/8  (fallback path only)
__global__ __launch_bounds__(256) void k_cvt(
    const float* __restrict__ src, unsigned short* __restrict__ dst, int n8)
{
    int i = blockIdx.x * 256 + threadIdx.x;
    if (i >= n8) return;
    const float* s = src + (size_t)i * 8;
    float4 a = *(const float4*)s, b = *(const float4*)(s + 4);
    unsigned int q[4] = { pack2(a.x, a.y), pack2(a.z, a.w), pack2(b.x, b.y), pack2(b.z, b.w) };
    *(s16x8*)(dst + (size_t)i * 8) = *(s16x8*)q;
}

// ---------------------------------------------------------------------------
// transpose (WqT only, 256x256 bf16): dst[dr][c] = src[c][dr]  (fallback only)
__global__ __launch_bounds__(256) void k_transpose(
    const unsigned short* __restrict__ src, unsigned short* __restrict__ dst,
    int RS, int DS)
{
    int dr = blockIdx.x * 256 + threadIdx.x;
    int c0 = blockIdx.y * 8;
    __align__(16) unsigned short tmp[8];
#pragma unroll
    for (int j = 0; j < 8; ++j) tmp[j] = src[(size_t)(c0 + j) * RS + dr];
    *(s16x8*)(dst + (size_t)dr * DS + c0) = *(s16x8*)tmp;
}

// ---------------------------------------------------------------------------
// merged weight prep: wb = bf16(w_qkv) [768x256]; wob = bf16(w_out) [256x256];
// WqT[c][hd] = bf16(w_qkv[hd][c]) for hd<256. grid 160 blocks x 256.
__global__ __launch_bounds__(256) void k_prepw(
    const float* __restrict__ wqkv, const float* __restrict__ wout,
    unsigned short* __restrict__ wb, unsigned short* __restrict__ wob,
    unsigned short* __restrict__ WqT)
{
    int i = blockIdx.x * 256 + threadIdx.x;
    if (i < 32768) {
        const float* s; unsigned short* d; int j;
        if (i < 24576) { s = wqkv; d = wb; j = i; }
        else           { s = wout; d = wob; j = i - 24576; }
        const float* sp = s + (size_t)j * 8;
        float4 a = *(const float4*)sp, b = *(const float4*)(sp + 4);
        unsigned int q[4] = { pack2(a.x, a.y), pack2(a.z, a.w), pack2(b.x, b.y), pack2(b.z, b.w) };
        *(s16x8*)(d + (size_t)j * 8) = *(s16x8*)q;
    } else {
        int j = i - 32768;                 // [0, 8192)
        int dr = j & 255, c0 = (j >> 8) * 8;
        __align__(16) unsigned short tmp[8];
#pragma unroll
        for (int jj = 0; jj < 8; ++jj)
            tmp[jj] = f2bits(wqkv[(size_t)(c0 + jj) * 256 + dr]);
        *(s16x8*)(WqT + (size_t)dr * 256 + c0) = *(s16x8*)tmp;
    }
}

// ---------------------------------------------------------------------------
// x [b][256 c][4096 n] f32  ->  xT [b][4096 n][256 c] bf16  AND
//                               xbf [b][256 c][4096 n] bf16 (same rounding)
__global__ __launch_bounds__(256) void k_prep(
    const float* __restrict__ x, unsigned short* __restrict__ xT,
    unsigned short* __restrict__ xbf)
{
    __shared__ unsigned short Ts[64][264];
    int b = blockIdx.y, n0 = blockIdx.x * 64, t = threadIdx.x;
    const float* xb = x + (size_t)b * 1048576;
    unsigned short* xbfb = xbf + (size_t)b * 1048576;
#pragma unroll
    for (int i = 0; i < 16; ++i) {
        int idx = t + i * 256;               // 0..4095
        int c = idx >> 4, nq = idx & 15;
        float4 v = *(const float4*)(xb + (size_t)c * 4096 + n0 + nq * 4);
        u32x2 q; q[0] = pack2(v.x, v.y); q[1] = pack2(v.z, v.w);
        *(u32x2*)(xbfb + (size_t)c * 4096 + n0 + nq * 4) = q;
        float vv[4] = { v.x, v.y, v.z, v.w };
#pragma unroll
        for (int e = 0; e < 4; ++e) {
            int ee = (e + c) & 3;            // rotate store order: spread LDS banks
            Ts[nq * 4 + ee][c] = f2bits(vv[ee]);
        }
    }
    __syncthreads();
    unsigned short* xTb = xT + (size_t)b * 1048576 + (size_t)n0 * 256;
#pragma unroll
    for (int i = 0; i < 8; ++i) {
        int idx = t + i * 256;               // 0..2047
        int nl = idx >> 5, cg = (idx & 31) * 8;
        *(s16x8*)(xTb + (size_t)nl * 256 + cg) = *(const s16x8*)&Ts[nl][cg];
    }
}

// ---------------------------------------------------------------------------
// gemm_bt2: C[m][n] = sum_k A[m][k] * Bt[n][k]; all bf16 operands.
// BM=BN=128, BK=64, block=256. Double-buffered global_load_lds staging
// (T3-min schedule: stage(nxt); compute(cur); vmcnt(0); s_barrier), linear
// LDS + XOR chunk swizzle (slot c of row r holds source chunk c^(r&7)).
// EPI==0: C bf16.  EPI==1: C f32, C = gamma[m]*(acc+bias[m]) + Xres[m][n].
template <int EPI>
__global__ __launch_bounds__(256) void gemm_bt2(
    const unsigned short* __restrict__ A, const unsigned short* __restrict__ Bt,
    void* __restrict__ C,
    int K, int Kstep, int lda, int ldb, int ldc,
    long Abs, long Bbs, long Cbs,
    const float* __restrict__ Xres,
    const float* __restrict__ gamma,
    const float* __restrict__ bias)
{
    __shared__ __align__(16) unsigned short As[2][128 * 64];
    __shared__ __align__(16) unsigned short Bs[2][128 * 64];
    int bz = blockIdx.z;
    int b = bz & 15, kc = bz >> 4;
    int m0 = blockIdx.y * 128, n0 = blockIdx.x * 128;
    const unsigned short* Ab = A + (size_t)b * Abs + (size_t)m0 * lda + (size_t)kc * Kstep;
    const unsigned short* Bb = Bt + (size_t)b * Bbs + (size_t)n0 * ldb + (size_t)kc * Kstep;
    int t = threadIdx.x;
    int w = t >> 6, l = t & 63, lm = l & 15, lq = l >> 4;
    int mw = (w >> 1) * 64, nw = (w & 1) * 64;

    f32x4 acc[4][4];
    f32x4 zero = {0.f, 0.f, 0.f, 0.f};
#pragma unroll
    for (int i = 0; i < 4; ++i)
#pragma unroll
        for (int j = 0; j < 4; ++j) acc[i][j] = zero;

    auto stage = [&](int buf, int kk) {
#pragma unroll
        for (int i = 0; i < 4; ++i) {
            int idx = t + i * 256;           // slot index; r=idx>>3, c=idx&7
            int r = idx >> 3;
            int sch = (idx & 7) ^ (r & 7);   // source chunk for this slot
            int lbase = (i * 256 + w * 64) * 8;  // wave-uniform LDS elem offset
            gl_lds16(Ab + (size_t)r * lda + kk + sch * 8, &As[buf][lbase]);
            gl_lds16(Bb + (size_t)r * ldb + kk + sch * 8, &Bs[buf][lbase]);
        }
    };
    auto compute = [&](int buf) {
#pragma unroll
        for (int ks = 0; ks < 2; ++ks) {
            s16x8 af[4], bfr[4];
#pragma unroll
            for (int mi = 0; mi < 4; ++mi) {
                int row = mw + mi * 16 + lm;
                af[mi] = *(const s16x8*)&As[buf][row * 64 + (((ks * 4 + lq) ^ (row & 7)) << 3)];
            }
#pragma unroll
            for (int ni = 0; ni < 4; ++ni) {
                int row = nw + ni * 16 + lm;
                bfr[ni] = *(const s16x8*)&Bs[buf][row * 64 + (((ks * 4 + lq) ^ (row & 7)) << 3)];
            }
#pragma unroll
            for (int mi = 0; mi < 4; ++mi)
#pragma unroll
                for (int ni = 0; ni < 4; ++ni)
                    acc[mi][ni] = __builtin_amdgcn_mfma_f32_16x16x32_bf16(af[mi], bfr[ni], acc[mi][ni], 0, 0, 0);
        }
    };

    // prologue: fill buf0, drain, join
    stage(0, 0);
    asm volatile("s_waitcnt vmcnt(0)" ::: "memory");
    __builtin_amdgcn_s_barrier();
    __builtin_amdgcn_sched_barrier(0);

    int cur = 0;
    for (int kk = 64; kk < K; kk += 64) {
        stage(cur ^ 1, kk);                  // next tile in flight during compute
        compute(cur);
        asm volatile("s_waitcnt vmcnt(0)" ::: "memory");
        __builtin_amdgcn_s_barrier();
        __builtin_amdgcn_sched_barrier(0);
        cur ^= 1;
    }
    compute(cur);                            // last tile (no prefetch)

    if (EPI == 0) {
        unsigned short* Cb = (unsigned short*)C + (size_t)bz * Cbs;
#pragma unroll
        for (int mi = 0; mi < 4; ++mi)
#pragma unroll
            for (int r = 0; r < 4; ++r) {
                int m = m0 + mw + mi * 16 + lq * 4 + r;
#pragma unroll
                for (int ni = 0; ni < 4; ++ni) {
                    int n = n0 + nw + ni * 16 + lm;
                    Cb[(size_t)m * ldc + n] = f2bits(acc[mi][ni][r]);
                }
            }
    } else {
        float* Cb = (float*)C + (size_t)bz * Cbs;
        const float* Xb = Xres + (size_t)bz * Cbs;
#pragma unroll
        for (int mi = 0; mi < 4; ++mi)
#pragma unroll
            for (int r = 0; r < 4; ++r) {
                int m = m0 + mw + mi * 16 + lq * 4 + r;
                float g = gamma[m], bo = bias[m];
#pragma unroll
                for (int ni = 0; ni < 4; ++ni) {
                    int n = n0 + nw + ni * 16 + lm;
                    size_t idx = (size_t)m * ldc + n;
                    Cb[idx] = g * (acc[mi][ni][r] + bo) + Xb[idx];
                }
            }
    }
}

// ---------------------------------------------------------------------------
// gemm64: 64x64-tile variant of gemm_bt2 (bf16 out), double-buffered the
// same way. Used by KG (K=2048, 32 pipelined iters) and W3.
__global__ __launch_bounds__(256) void gemm64(
    const unsigned short* __restrict__ A, const unsigned short* __restrict__ Bt,
    unsigned short* __restrict__ C,
    int K, int Kstep, int lda, int ldb, int ldc,
    long Abs, long Bbs, long Cbs)
{
    __shared__ __align__(16) unsigned short As[2][64 * 64];
    __shared__ __align__(16) unsigned short Bs[2][64 * 64];
    int bz = blockIdx.z;
    int b = bz & 15, kc = bz >> 4;
    int m0 = blockIdx.y * 64, n0 = blockIdx.x * 64;
    const unsigned short* Ab = A + (size_t)b * Abs + (size_t)m0 * lda + (size_t)kc * Kstep;
    const unsigned short* Bb = Bt + (size_t)b * Bbs + (size_t)n0 * ldb + (size_t)kc * Kstep;
    int t = threadIdx.x;
    int w = t >> 6, l = t & 63, lm = l & 15, lq = l >> 4;
    int mw = (w >> 1) * 32, nw = (w & 1) * 32;

    f32x4 acc[2][2];
    f32x4 zero = {0.f, 0.f, 0.f, 0.f};
#pragma unroll
    for (int i = 0; i < 2; ++i)
#pragma unroll
        for (int j = 0; j < 2; ++j) acc[i][j] = zero;

    auto stage = [&](int buf, int kk) {
#pragma unroll
        for (int i = 0; i < 2; ++i) {
            int idx = t + i * 256;           // 0..511
            int r = idx >> 3;
            int sch = (idx & 7) ^ (r & 7);
            int lbase = (i * 256 + w * 64) * 8;
            gl_lds16(Ab + (size_t)r * lda + kk + sch * 8, &As[buf][lbase]);
            gl_lds16(Bb + (size_t)r * ldb + kk + sch * 8, &Bs[buf][lbase]);
        }
    };
    auto compute = [&](int buf) {
#pragma unroll
        for (int ks = 0; ks < 2; ++ks) {
            s16x8 af[2], bfr[2];
#pragma unroll
            for (int mi = 0; mi < 2; ++mi) {
                int row = mw + mi * 16 + lm;
                af[mi] = *(const s16x8*)&As[buf][row * 64 + (((ks * 4 + lq) ^ (row & 7)) << 3)];
            }
#pragma unroll
            for (int ni = 0; ni < 2; ++ni) {
                int row = nw + ni * 16 + lm;
                bfr[ni] = *(const s16x8*)&Bs[buf][row * 64 + (((ks * 4 + lq) ^ (row & 7)) << 3)];
            }
#pragma unroll
            for (int mi = 0; mi < 2; ++mi)
#pragma unroll
                for (int ni = 0; ni < 2; ++ni)
                    acc[mi][ni] = __builtin_amdgcn_mfma_f32_16x16x32_bf16(af[mi], bfr[ni], acc[mi][ni], 0, 0, 0);
        }
    };

    stage(0, 0);
    asm volatile("s_waitcnt vmcnt(0)" ::: "memory");
    __builtin_amdgcn_s_barrier();
    __builtin_amdgcn_sched_barrier(0);

    int cur = 0;
    for (int kk = 64; kk < K; kk += 64) {
        stage(cur ^ 1, kk);
        compute(cur);
        asm volatile("s_waitcnt vmcnt(0)" ::: "memory");
        __builtin_amdgcn_s_barrier();
        __builtin_amdgcn_sched_barrier(0);
        cur ^= 1;
    }
    compute(cur);

    unsigned short* Cb = C + (size_t)bz * Cbs;
#pragma unroll
    for (int mi = 0; mi < 2; ++mi)
#pragma unroll
        for (int r = 0; r < 4; ++r) {
            int m = m0 + mw + mi * 16 + lq * 4 + r;
#pragma unroll
            for (int ni = 0; ni < 2; ++ni) {
                int n = n0 + nw + ni * 16 + lm;
                Cb[(size_t)m * ldc + n] = f2bits(acc[mi][ni][r]);
            }
        }
}

// ---------------------------------------------------------------------------
// gemm_bt (fallback path only): reg-staged, padded LDS, optional f32 B.
template <int BF32, int EPI>
__global__ __launch_bounds__(256) void gemm_bt(
    const unsigned short* __restrict__ A, const void* __restrict__ Bt,
    void* __restrict__ C,
    int K, int Kstep, int lda, int ldb, int ldc,
    long Abs, long Bbs, long Cbs,
    const float* __restrict__ Xres,
    const float* __restrict__ gamma,
    const float* __restrict__ bias)
{
    __shared__ unsigned short As[128][72];
    __shared__ unsigned short Bs[128][72];
    int bz = blockIdx.z;
    int b = bz & 15, kc = bz >> 4;
    int m0 = blockIdx.y * 128, n0 = blockIdx.x * 128;
    const unsigned short* Ab = A + (size_t)b * Abs + (size_t)m0 * lda + (size_t)kc * Kstep;
    size_t boff = (size_t)b * Bbs + (size_t)n0 * ldb + (size_t)kc * Kstep;
    int t = threadIdx.x;
    int w = t >> 6, l = t & 63, lm = l & 15, lq = l >> 4;
    int mw = (w >> 1) * 64, nw = (w & 1) * 64;

    f32x4 acc[4][4];
    f32x4 zero = {0.f, 0.f, 0.f, 0.f};
#pragma unroll
    for (int i = 0; i < 4; ++i)
#pragma unroll
        for (int j = 0; j < 4; ++j) acc[i][j] = zero;

    for (int kk = 0; kk < K; kk += 64) {
#pragma unroll
        for (int i = 0; i < 4; ++i) {
            int idx = t + i * 256;
            int r = idx >> 3, ch = idx & 7;
            *(s16x8*)&As[r][ch * 8] = *(const s16x8*)(Ab + (size_t)r * lda + kk + ch * 8);
            if (BF32) {
                const float* bp = (const float*)Bt + boff + (size_t)r * ldb + kk + ch * 8;
                float4 v0 = *(const float4*)bp, v1 = *(const float4*)(bp + 4);
                unsigned int q[4] = { pack2(v0.x, v0.y), pack2(v0.z, v0.w),
                                      pack2(v1.x, v1.y), pack2(v1.z, v1.w) };
                *(s16x8*)&Bs[r][ch * 8] = *(s16x8*)q;
            } else {
                const unsigned short* bp = (const unsigned short*)Bt + boff + (size_t)r * ldb + kk + ch * 8;
                *(s16x8*)&Bs[r][ch * 8] = *(const s16x8*)bp;
            }
        }
        __syncthreads();
#pragma unroll
        for (int ks = 0; ks < 2; ++ks) {
            s16x8 af[4], bfr[4];
#pragma unroll
            for (int mi = 0; mi < 4; ++mi) af[mi]  = *(const s16x8*)&As[mw + mi * 16 + lm][ks * 32 + lq * 8];
#pragma unroll
            for (int ni = 0; ni < 4; ++ni) bfr[ni] = *(const s16x8*)&Bs[nw + ni * 16 + lm][ks * 32 + lq * 8];
#pragma unroll
            for (int mi = 0; mi < 4; ++mi)
#pragma unroll
                for (int ni = 0; ni < 4; ++ni)
                    acc[mi][ni] = __builtin_amdgcn_mfma_f32_16x16x32_bf16(af[mi], bfr[ni], acc[mi][ni], 0, 0, 0);
        }
        __syncthreads();
    }

    if (EPI == 0) {
        unsigned short* Cb = (unsigned short*)C + (size_t)bz * Cbs;
#pragma unroll
        for (int mi = 0; mi < 4; ++mi)
#pragma unroll
            for (int r = 0; r < 4; ++r) {
                int m = m0 + mw + mi * 16 + lq * 4 + r;
#pragma unroll
                for (int ni = 0; ni < 4; ++ni) {
                    int n = n0 + nw + ni * 16 + lm;
                    Cb[(size_t)m * ldc + n] = f2bits(acc[mi][ni][r]);
                }
            }
    } else {
        float* Cb = (float*)C + (size_t)bz * Cbs;
        const float* Xb = Xres + (size_t)bz * Cbs;
#pragma unroll
        for (int mi = 0; mi < 4; ++mi)
#pragma unroll
            for (int r = 0; r < 4; ++r) {
                int m = m0 + mw + mi * 16 + lq * 4 + r;
                float g = gamma[m], bo = bias[m];
#pragma unroll
                for (int ni = 0; ni < 4; ++ni) {
                    int n = n0 + nw + ni * 16 + lm;
                    size_t idx = (size_t)m * ldc + n;
                    Cb[idx] = g * (acc[mi][ni][r] + bo) + Xb[idx];
                }
            }
    }
}

// ---------------------------------------------------------------------------
// gemm_bn (fallback path only): C[m][n] = sum_k A[m][k] * B[k][n]
template <int EPI>
__global__ __launch_bounds__(256) void gemm_bn(
    const unsigned short* __restrict__ A, const float* __restrict__ B,
    void* __restrict__ C,
    int K, int lda, int ldb, int ldc,
    long Abs, long Bbs, long Cbs,
    const float* __restrict__ Xres,
    const float* __restrict__ gamma,
    const float* __restrict__ bias)
{
    __shared__ unsigned short As[128][72];
    __shared__ unsigned short Bs[64][130];
    int bz = blockIdx.z;
    int m0 = blockIdx.y * 128, n0 = blockIdx.x * 128;
    const unsigned short* Ab = A + (size_t)bz * Abs + (size_t)m0 * lda;
    const float* Bb = B + (size_t)bz * Bbs + n0;
    int t = threadIdx.x;
    int w = t >> 6, l = t & 63, lm = l & 15, lq = l >> 4;
    int mw = (w >> 1) * 64, nw = (w & 1) * 64;

    f32x4 acc[4][4];
    f32x4 zero = {0.f, 0.f, 0.f, 0.f};
#pragma unroll
    for (int i = 0; i < 4; ++i)
#pragma unroll
        for (int j = 0; j < 4; ++j) acc[i][j] = zero;

    for (int kk = 0; kk < K; kk += 64) {
#pragma unroll
        for (int i = 0; i < 4; ++i) {
            int idx = t + i * 256;
            int r = idx >> 3, ch = idx & 7;
            *(s16x8*)&As[r][ch * 8] = *(const s16x8*)(Ab + (size_t)r * lda + kk + ch * 8);
        }
#pragma unroll
        for (int i = 0; i < 4; ++i) {
            int idx = t + i * 256;
            int c = idx >> 4, cc = idx & 15;
            const float* bp = Bb + (size_t)(kk + c) * ldb + cc * 8;
            float4 v0 = *(const float4*)bp, v1 = *(const float4*)(bp + 4);
            unsigned int* q = (unsigned int*)&Bs[c][cc * 8];
            q[0] = pack2(v0.x, v0.y); q[1] = pack2(v0.z, v0.w);
            q[2] = pack2(v1.x, v1.y); q[3] = pack2(v1.z, v1.w);
        }
        __syncthreads();
#pragma unroll
        for (int ks = 0; ks < 2; ++ks) {
            s16x8 af[4];
#pragma unroll
            for (int mi = 0; mi < 4; ++mi) af[mi] = *(const s16x8*)&As[mw + mi * 16 + lm][ks * 32 + lq * 8];
#pragma unroll
            for (int ni = 0; ni < 4; ++ni) {
                s16x8 bfr;
#pragma unroll
                for (int j = 0; j < 8; ++j) bfr[j] = (short)Bs[ks * 32 + lq * 8 + j][nw + ni * 16 + lm];
#pragma unroll
                for (int mi = 0; mi < 4; ++mi)
                    acc[mi][ni] = __builtin_amdgcn_mfma_f32_16x16x32_bf16(af[mi], bfr, acc[mi][ni], 0, 0, 0);
            }
        }
        __syncthreads();
    }

#pragma unroll
    for (int mi = 0; mi < 4; ++mi)
#pragma unroll
        for (int r = 0; r < 4; ++r) {
            int m = m0 + mw + mi * 16 + lq * 4 + r;
            float g = 0.f, bo = 0.f;
            if (EPI == 1) { g = gamma[m]; bo = bias[m]; }
#pragma unroll
            for (int ni = 0; ni < 4; ++ni) {
                int n = n0 + nw + ni * 16 + lm;
                size_t idx = (size_t)m * ldc + n;
                float v = acc[mi][ni][r];
                if (EPI == 1) {
                    float* Cb = (float*)C + (size_t)bz * Cbs;
                    Cb[idx] = g * (v + bo) + Xres[(size_t)bz * Cbs + idx];
                } else {
                    unsigned short* Cb = (unsigned short*)C + (size_t)bz * Cbs;
                    Cb[idx] = f2bits(v);
                }
            }
        }
}

// ---------------------------------------------------------------------------
// softmax over n (4096) for each of 4096 rows of kbuf (bf16)
__global__ __launch_bounds__(256) void k_softmax(unsigned short* __restrict__ kbuf)
{
    unsigned short* p = kbuf + (size_t)blockIdx.x * 4096;
    int t = threadIdx.x;
    __shared__ float red[4];

    s16x8 r0 = *(const s16x8*)(p + t * 16);
    s16x8 r1 = *(const s16x8*)(p + t * 16 + 8);
    float v[16];
    float m = -1e30f;
#pragma unroll
    for (int i = 0; i < 8; ++i) { v[i] = bits2f((unsigned short)r0[i]); v[8 + i] = bits2f((unsigned short)r1[i]); }
#pragma unroll
    for (int i = 0; i < 16; ++i) m = fmaxf(m, v[i]);
#pragma unroll
    for (int off = 32; off >= 1; off >>= 1) m = fmaxf(m, __shfl_xor(m, off));
    if ((t & 63) == 0) red[t >> 6] = m;
    __syncthreads();
    m = fmaxf(fmaxf(red[0], red[1]), fmaxf(red[2], red[3]));
    __syncthreads();

    float s = 0.f;
#pragma unroll
    for (int i = 0; i < 16; ++i) { v[i] = __expf(v[i] - m); s += v[i]; }
#pragma unroll
    for (int off = 32; off >= 1; off >>= 1) s += __shfl_xor(s, off);
    if ((t & 63) == 0) red[t >> 6] = s;
    __syncthreads();
    s = red[0] + red[1] + red[2] + red[3];
    float inv = 1.0f / s;

    __align__(16) unsigned short otmp[16];
#pragma unroll
    for (int i = 0; i < 16; ++i) otmp[i] = f2bits(v[i] * inv);
    *(s16x8*)(p + t * 16) = *(s16x8*)(otmp);
    *(s16x8*)(p + t * 16 + 8) = *(s16x8*)(otmp + 8);
}

// ---------------------------------------------------------------------------
// G[b][i] = sum_{kc<NC} Gp[kc*16+b][i]
template <int NC>
__global__ __launch_bounds__(256) void k_gred(
    const unsigned short* __restrict__ Gp, unsigned short* __restrict__ G)
{
    int gid = blockIdx.x * 256 + threadIdx.x;   // [0, 131072)
    int b = gid >> 13;
    size_t i8 = (size_t)(gid & 8191) * 8;
    float s[8] = {0.f, 0.f, 0.f, 0.f, 0.f, 0.f, 0.f, 0.f};
#pragma unroll
    for (int kc = 0; kc < NC; ++kc) {
        s16x8 v = *(const s16x8*)(Gp + (size_t)(kc * 16 + b) * 65536 + i8);
#pragma unroll
        for (int j = 0; j < 8; ++j) s[j] += bits2f((unsigned short)v[j]);
    }
    __align__(16) unsigned short tmp[8];
#pragma unroll
    for (int j = 0; j < 8; ++j) tmp[j] = f2bits(s[j]);
    *(s16x8*)(G + (size_t)b * 65536 + i8) = *(s16x8*)tmp;
}

// ---------------------------------------------------------------------------
// per (b,h): ctx[d][e] = sum_c G[b][h*64+d][c] * Wv[h*64+e][c]  (K=256)
// then      W2[b][o][h*64+d] = sum_e w_out[o][h*64+e] * ctx[d][e] (K=64)
__global__ __launch_bounds__(256) void k_ctxw2(
    const unsigned short* __restrict__ G, const unsigned short* __restrict__ wb,
    const unsigned short* __restrict__ wob, unsigned short* __restrict__ W2)
{
    __shared__ unsigned short ctxs[64][72];
    int h = blockIdx.x, b = blockIdx.y;
    int t = threadIdx.x, w = t >> 6, l = t & 63, lm = l & 15, lq = l >> 4;
    const unsigned short* Gb = G + (size_t)b * 65536 + (size_t)(h * 64) * 256;
    const unsigned short* Wv = wb + 131072 + (size_t)(h * 64) * 256;
    f32x4 zero = {0.f, 0.f, 0.f, 0.f};

    f32x4 acc[4];
#pragma unroll
    for (int i = 0; i < 4; ++i) acc[i] = zero;
    for (int kk = 0; kk < 256; kk += 32) {
        s16x8 a = *(const s16x8*)(Gb + (size_t)(w * 16 + lm) * 256 + kk + lq * 8);
#pragma unroll
        for (int ni = 0; ni < 4; ++ni) {
            s16x8 bb = *(const s16x8*)(Wv + (size_t)(ni * 16 + lm) * 256 + kk + lq * 8);
            acc[ni] = __builtin_amdgcn_mfma_f32_16x16x32_bf16(a, bb, acc[ni], 0, 0, 0);
        }
    }
#pragma unroll
    for (int ni = 0; ni < 4; ++ni)
#pragma unroll
        for (int r = 0; r < 4; ++r)
            ctxs[w * 16 + lq * 4 + r][ni * 16 + lm] = f2bits(acc[ni][r]);
    __syncthreads();

    f32x4 acc2[4][4];
#pragma unroll
    for (int i = 0; i < 4; ++i)
#pragma unroll
        for (int j = 0; j < 4; ++j) acc2[i][j] = zero;
#pragma unroll
    for (int ks = 0; ks < 2; ++ks) {
        s16x8 af[4], bfr[4];
#pragma unroll
        for (int mi = 0; mi < 4; ++mi)
            af[mi] = *(const s16x8*)(wob + (size_t)(w * 64 + mi * 16 + lm) * 256 + h * 64 + ks * 32 + lq * 8);
#pragma unroll
        for (int ni = 0; ni < 4; ++ni) bfr[ni] = *(const s16x8*)&ctxs[ni * 16 + lm][ks * 32 + lq * 8];
#pragma unroll
        for (int mi = 0; mi < 4; ++mi)
#pragma unroll
            for (int ni = 0; ni < 4; ++ni)
                acc2[mi][ni] = __builtin_amdgcn_mfma_f32_16x16x32_bf16(af[mi], bfr[ni], acc2[mi][ni], 0, 0, 0);
    }
    unsigned short* W2b = W2 + (size_t)b * 65536;
#pragma unroll
    for (int mi = 0; mi < 4; ++mi)
#pragma unroll
        for (int r = 0; r < 4; ++r) {
            int o = w * 64 + mi * 16 + lq * 4 + r;
#pragma unroll
            for (int ni = 0; ni < 4; ++ni)
                W2b[(size_t)o * 256 + h * 64 + ni * 16 + lm] = f2bits(acc2[mi][ni][r]);
        }
}

// ---------------------------------------------------------------------------
extern "C" void kernel_launch(void* const* d_in, const int* in_sizes, int n_in,
                              void* d_out, int out_size, void* d_ws, size_t ws_size,
                              hipStream_t stream)
{
    (void)in_sizes; (void)n_in; (void)out_size;
    const float* x      = (const float*)d_in[0]; // [16][256][4096] f32
    const float* w_qkv  = (const float*)d_in[1]; // [768][256] f32
    const float* w_out  = (const float*)d_in[2]; // [256][256] f32
    const float* b_out  = (const float*)d_in[3]; // [256] f32
    const float* gamma  = (const float*)d_in[4]; // [256] f32

    char* ws = (char*)d_ws;
    const size_t NEED = 40501248;

    if (ws_size >= NEED) {
        // ws layout (40,501,248 B total):
        unsigned short* xT  = (unsigned short*)ws;                    // [16][4096][256] bf16 = 33,554,432
        unsigned short* W3  = (unsigned short*)(ws + 33554432);       //  2,097,152
        unsigned short* Gp  = (unsigned short*)(ws + 35651584);       //  4,194,304 (kc=2 split)
        unsigned short* WqT = (unsigned short*)(ws + 39845888);       //    131,072
        unsigned short* wb  = (unsigned short*)(ws + 39976960);       //    393,216
        unsigned short* wob = (unsigned short*)(ws + 40370176);       //    131,072
        // d_out (64MB) as scratch until K5 rewrites it:
        unsigned short* kbuf = (unsigned short*)d_out;                // [0, 32MB) — dead after KG
        unsigned short* xbf  = (unsigned short*)d_out + 16777216;     // [32MB, 64MB) — dead after KG
        unsigned short* G    = (unsigned short*)d_out;                // overlays dead kbuf (2MB)
        unsigned short* W2   = (unsigned short*)d_out + 1048576;      // +2MB (2MB) — dead before K5

        // weights: wb/wob bf16 + WqT
        k_prepw<<<dim3(160), 256, 0, stream>>>(w_qkv, w_out, wb, wob, WqT);

        // xT = transpose(x) bf16; xbf = x bf16 (same layout)
        k_prep<<<dim3(64, 16), 256, 0, stream>>>(x, xT, xbf);

        // K1: k = Wk @ x  == gemm_bt2(A=Wk, Bt=xT)   (M=256,N=4096,K=256)
        gemm_bt2<0><<<dim3(32, 2, 16), 256, 0, stream>>>(
            wb + 65536, xT, kbuf, 256, 0, 256, 256, 4096,
            0L, 1048576L, 1048576L, nullptr, nullptr, nullptr);

        // K2: softmax rows of k
        k_softmax<<<dim3(4096), 256, 0, stream>>>(kbuf);

        // KG: Gp[kc*16+b] = softk_b[:,chunk] @ xbf_b[:,chunk]^T (K-split x2, 64² tiles)
        gemm64<<<dim3(4, 4, 32), 256, 0, stream>>>(
            kbuf, xbf, Gp, 2048, 2048, 4096, 4096, 256,
            1048576L, 1048576L, 65536L);

        // G = sum_kc Gp  (G overlays dead kbuf region)
        k_gred<2><<<dim3(512), 256, 0, stream>>>(Gp, G);

        // ctx + W2 fused per (b,h)
        k_ctxw2<<<dim3(4, 16), 256, 0, stream>>>(G, wb, wob, W2);

        // W3[b] = W2[b] @ Wq
        gemm64<<<dim3(4, 4, 16), 256, 0, stream>>>(
            W2, WqT, W3, 256, 0, 256, 256, 256,
            65536L, 0L, 65536L);

        // K5: out(f32) = gamma*(W3 @ x + b_out) + x  == gemm_bt2<1>(A=W3, Bt=xT)
        gemm_bt2<1><<<dim3(32, 2, 16), 256, 0, stream>>>(
            W3, xT, d_out, 256, 0, 256, 256, 4096,
            65536L, 1048576L, 1048576L, x, gamma, b_out);
    } else {
        // ---- fallback: previously verified path (23,724,032 B of ws) ----
        unsigned short* kbuf = (unsigned short*)d_out;
        unsigned short* Gp  = (unsigned short*)(ws);                  // 16,777,216
        unsigned short* G   = (unsigned short*)(ws + 16777216);       //  2,097,152
        unsigned short* W2  = (unsigned short*)(ws + 18874368);       //  2,097,152
        unsigned short* W3  = (unsigned short*)(ws + 20971520);       //  2,097,152
        unsigned short* WqT = (unsigned short*)(ws + 23068672);       //    131,072
        unsigned short* wb  = (unsigned short*)(ws + 23199744);       //    393,216
        unsigned short* wob = (unsigned short*)(ws + 23592960);       //    131,072

        k_cvt<<<dim3(96), 256, 0, stream>>>(w_qkv, wb, 24576);
        k_cvt<<<dim3(32), 256, 0, stream>>>(w_out, wob, 8192);
        k_transpose<<<dim3(1, 32, 1), 256, 0, stream>>>(wb, WqT, 256, 256);

        gemm_bn<0><<<dim3(32, 2, 16), 256, 0, stream>>>(
            wb + 65536, x, kbuf, 256, 256, 4096, 4096,
            0L, 1048576L, 1048576L, nullptr, nullptr, nullptr);

        k_softmax<<<dim3(4096), 256, 0, stream>>>(kbuf);

        gemm_bt<1, 0><<<dim3(2, 2, 128), 256, 0, stream>>>(
            kbuf, x, Gp, 512, 512, 4096, 4096, 256,
            1048576L, 1048576L, 65536L, nullptr, nullptr, nullptr);

        k_gred<8><<<dim3(512), 256, 0, stream>>>(Gp, G);
        k_ctxw2<<<dim3(4, 16), 256, 0, stream>>>(G, wb, wob, W2);

        gemm_bt<0, 0><<<dim3(2, 2, 16), 256, 0, stream>>>(
            W2, WqT, W3, 256, 0, 256, 256, 256,
            65536L, 0L, 65536L, nullptr, nullptr, nullptr);

        gemm_bn<1><<<dim3(32, 2, 16), 256, 0, stream>>>(
            W3, x, d_out, 256, 256, 4096, 4096,
            65536L, 1048576L, 1048576L, x, gamma, b_out);
    }
}

// Round 5
// 228.931 us; speedup vs baseline: 1.0138x; 1.0023x over previous
//
#include <hip/hip_runtime.h>
#include <stdint.h>

typedef short s16x8 __attribute__((ext_vector_type(8)));
typedef float f32x4 __attribute__((ext_vector_type(4)));
typedef unsigned int u32x2 __attribute__((ext_vector_type(2)));

typedef const __attribute__((address_space(1))) void glb_cv;
typedef __attribute__((address_space(3))) void lds_v;

__device__ __forceinline__ float bits2f(unsigned short u) {
    union { unsigned int i; float f; } c; c.i = ((unsigned int)u) << 16; return c.f;
}
__device__ __forceinline__ unsigned short f2bits(float f) {
    union { float f; unsigned int i; } c; c.f = f;
    unsigned int x = c.i;
    unsigned int r = (x + 0x7FFFu + ((x >> 16) & 1u)) >> 16;
    return (unsigned short)r;
}
__device__ __forceinline__ unsigned int pack2(float a, float b) {
    return (unsigned int)f2bits(a) | ((unsigned int)f2bits(b) << 16);
}

// async global->LDS, 16B per lane. LDS dest = wave-uniform base + lane*16.
__device__ __forceinline__ void gl_lds16(const void* g, void* l) {
    __builtin_amdgcn_global_load_lds((glb_cv*)g, (lds_v*)l, 16, 0, 0);
}

// ---------------------------------------------------------------------------
// f32 -> bf16 bulk convert; n8 = n/8  (fallback path only)
__global__ __launch_bounds__(256) void k_cvt(
    const float* __restrict__ src, unsigned short* __restrict__ dst, int n8)
{
    int i = blockIdx.x * 256 + threadIdx.x;
    if (i >= n8) return;
    const float* s = src + (size_t)i * 8;
    float4 a = *(const float4*)s, b = *(const float4*)(s + 4);
    unsigned int q[4] = { pack2(a.x, a.y), pack2(a.z, a.w), pack2(b.x, b.y), pack2(b.z, b.w) };
    *(s16x8*)(dst + (size_t)i * 8) = *(s16x8*)q;
}

// ---------------------------------------------------------------------------
// transpose (WqT only, 256x256 bf16): dst[dr][c] = src[c][dr]  (fallback only)
__global__ __launch_bounds__(256) void k_transpose(
    const unsigned short* __restrict__ src, unsigned short* __restrict__ dst,
    int RS, int DS)
{
    int dr = blockIdx.x * 256 + threadIdx.x;
    int c0 = blockIdx.y * 8;
    __align__(16) unsigned short tmp[8];
#pragma unroll
    for (int j = 0; j < 8; ++j) tmp[j] = src[(size_t)(c0 + j) * RS + dr];
    *(s16x8*)(dst + (size_t)dr * DS + c0) = *(s16x8*)tmp;
}

// ---------------------------------------------------------------------------
// merged weight prep: wb = bf16(w_qkv) [768x256]; wob = bf16(w_out) [256x256];
// WqT[c][hd] = bf16(w_qkv[hd][c]) for hd<256. grid 160 blocks x 256.
__global__ __launch_bounds__(256) void k_prepw(
    const float* __restrict__ wqkv, const float* __restrict__ wout,
    unsigned short* __restrict__ wb, unsigned short* __restrict__ wob,
    unsigned short* __restrict__ WqT)
{
    int i = blockIdx.x * 256 + threadIdx.x;
    if (i < 32768) {
        const float* s; unsigned short* d; int j;
        if (i < 24576) { s = wqkv; d = wb; j = i; }
        else           { s = wout; d = wob; j = i - 24576; }
        const float* sp = s + (size_t)j * 8;
        float4 a = *(const float4*)sp, b = *(const float4*)(sp + 4);
        unsigned int q[4] = { pack2(a.x, a.y), pack2(a.z, a.w), pack2(b.x, b.y), pack2(b.z, b.w) };
        *(s16x8*)(d + (size_t)j * 8) = *(s16x8*)q;
    } else {
        int j = i - 32768;                 // [0, 8192)
        int dr = j & 255, c0 = (j >> 8) * 8;
        __align__(16) unsigned short tmp[8];
#pragma unroll
        for (int jj = 0; jj < 8; ++jj)
            tmp[jj] = f2bits(wqkv[(size_t)(c0 + jj) * 256 + dr]);
        *(s16x8*)(WqT + (size_t)dr * 256 + c0) = *(s16x8*)tmp;
    }
}

// ---------------------------------------------------------------------------
// x [b][256 c][4096 n] f32  ->  xT [b][4096 n][256 c] bf16  AND
//                               xbf [b][256 c][4096 n] bf16 (same rounding)
__global__ __launch_bounds__(256) void k_prep(
    const float* __restrict__ x, unsigned short* __restrict__ xT,
    unsigned short* __restrict__ xbf)
{
    __shared__ unsigned short Ts[64][264];
    int b = blockIdx.y, n0 = blockIdx.x * 64, t = threadIdx.x;
    const float* xb = x + (size_t)b * 1048576;
    unsigned short* xbfb = xbf + (size_t)b * 1048576;
#pragma unroll
    for (int i = 0; i < 16; ++i) {
        int idx = t + i * 256;               // 0..4095
        int c = idx >> 4, nq = idx & 15;
        float4 v = *(const float4*)(xb + (size_t)c * 4096 + n0 + nq * 4);
        u32x2 q; q[0] = pack2(v.x, v.y); q[1] = pack2(v.z, v.w);
        *(u32x2*)(xbfb + (size_t)c * 4096 + n0 + nq * 4) = q;
        float vv[4] = { v.x, v.y, v.z, v.w };
#pragma unroll
        for (int e = 0; e < 4; ++e) {
            int ee = (e + c) & 3;            // rotate store order: spread LDS banks
            Ts[nq * 4 + ee][c] = f2bits(vv[ee]);
        }
    }
    __syncthreads();
    unsigned short* xTb = xT + (size_t)b * 1048576 + (size_t)n0 * 256;
#pragma unroll
    for (int i = 0; i < 8; ++i) {
        int idx = t + i * 256;               // 0..2047
        int nl = idx >> 5, cg = (idx & 31) * 8;
        *(s16x8*)(xTb + (size_t)nl * 256 + cg) = *(const s16x8*)&Ts[nl][cg];
    }
}

// ---------------------------------------------------------------------------
// gemm_bt2: C[m][n] = sum_k A[m][k] * Bt[n][k]; all bf16 operands.
// BM=BN=128, BK=32, block=256, 4+ blocks/CU (32KB LDS, VGPR<=128).
// Double-buffered global_load_lds staging (stage(nxt); compute(cur);
// vmcnt(0); s_barrier). Linear LDS + XOR chunk swizzle: slot c of row r
// holds source chunk c^(r&3) (4 chunks of 8 elems per 32-elem row);
// involution applied on stage-source and read side.
// EPI==0: C bf16.  EPI==1: C f32, C = gamma[m]*(acc+bias[m]) + Xres[m][n].
template <int EPI>
__global__ __launch_bounds__(256, 4) void gemm_bt2(
    const unsigned short* __restrict__ A, const unsigned short* __restrict__ Bt,
    void* __restrict__ C,
    int K, int Kstep, int lda, int ldb, int ldc,
    long Abs, long Bbs, long Cbs,
    const float* __restrict__ Xres,
    const float* __restrict__ gamma,
    const float* __restrict__ bias)
{
    __shared__ __align__(16) unsigned short As[2][128 * 32];
    __shared__ __align__(16) unsigned short Bs[2][128 * 32];
    int bz = blockIdx.z;
    int b = bz & 15, kc = bz >> 4;
    int m0 = blockIdx.y * 128, n0 = blockIdx.x * 128;
    const unsigned short* Ab = A + (size_t)b * Abs + (size_t)m0 * lda + (size_t)kc * Kstep;
    const unsigned short* Bb = Bt + (size_t)b * Bbs + (size_t)n0 * ldb + (size_t)kc * Kstep;
    int t = threadIdx.x;
    int w = t >> 6, l = t & 63, lm = l & 15, lq = l >> 4;
    int mw = (w >> 1) * 64, nw = (w & 1) * 64;

    f32x4 acc[4][4];
    f32x4 zero = {0.f, 0.f, 0.f, 0.f};
#pragma unroll
    for (int i = 0; i < 4; ++i)
#pragma unroll
        for (int j = 0; j < 4; ++j) acc[i][j] = zero;

    auto stage = [&](int buf, int kk) {
#pragma unroll
        for (int i = 0; i < 2; ++i) {
            int idx = t + i * 256;           // slot index 0..511; r=idx>>2, c=idx&3
            int r = idx >> 2;
            int sch = (idx & 3) ^ (r & 3);   // source chunk for this slot
            int lbase = (i * 256 + w * 64) * 8;  // wave-uniform LDS elem offset
            gl_lds16(Ab + (size_t)r * lda + kk + sch * 8, &As[buf][lbase]);
            gl_lds16(Bb + (size_t)r * ldb + kk + sch * 8, &Bs[buf][lbase]);
        }
    };
    auto compute = [&](int buf) {
        s16x8 af[4], bfr[4];
#pragma unroll
        for (int mi = 0; mi < 4; ++mi) {
            int row = mw + mi * 16 + lm;
            af[mi] = *(const s16x8*)&As[buf][row * 32 + ((lq ^ (row & 3)) << 3)];
        }
#pragma unroll
        for (int ni = 0; ni < 4; ++ni) {
            int row = nw + ni * 16 + lm;
            bfr[ni] = *(const s16x8*)&Bs[buf][row * 32 + ((lq ^ (row & 3)) << 3)];
        }
#pragma unroll
        for (int mi = 0; mi < 4; ++mi)
#pragma unroll
            for (int ni = 0; ni < 4; ++ni)
                acc[mi][ni] = __builtin_amdgcn_mfma_f32_16x16x32_bf16(af[mi], bfr[ni], acc[mi][ni], 0, 0, 0);
    };

    // prologue: fill buf0, drain, join
    stage(0, 0);
    asm volatile("s_waitcnt vmcnt(0)" ::: "memory");
    __builtin_amdgcn_s_barrier();
    __builtin_amdgcn_sched_barrier(0);

    int cur = 0;
    for (int kk = 32; kk < K; kk += 32) {
        stage(cur ^ 1, kk);                  // next tile in flight during compute
        compute(cur);
        asm volatile("s_waitcnt vmcnt(0)" ::: "memory");
        __builtin_amdgcn_s_barrier();
        __builtin_amdgcn_sched_barrier(0);
        cur ^= 1;
    }
    compute(cur);                            // last tile (no prefetch)

    if (EPI == 0) {
        unsigned short* Cb = (unsigned short*)C + (size_t)bz * Cbs;
#pragma unroll
        for (int mi = 0; mi < 4; ++mi)
#pragma unroll
            for (int r = 0; r < 4; ++r) {
                int m = m0 + mw + mi * 16 + lq * 4 + r;
#pragma unroll
                for (int ni = 0; ni < 4; ++ni) {
                    int n = n0 + nw + ni * 16 + lm;
                    Cb[(size_t)m * ldc + n] = f2bits(acc[mi][ni][r]);
                }
            }
    } else {
        float* Cb = (float*)C + (size_t)bz * Cbs;
        const float* Xb = Xres + (size_t)bz * Cbs;
#pragma unroll
        for (int mi = 0; mi < 4; ++mi)
#pragma unroll
            for (int r = 0; r < 4; ++r) {
                int m = m0 + mw + mi * 16 + lq * 4 + r;
                float g = gamma[m], bo = bias[m];
#pragma unroll
                for (int ni = 0; ni < 4; ++ni) {
                    int n = n0 + nw + ni * 16 + lm;
                    size_t idx = (size_t)m * ldc + n;
                    Cb[idx] = g * (acc[mi][ni][r] + bo) + Xb[idx];
                }
            }
    }
}

// ---------------------------------------------------------------------------
// gemm64: 64x64-tile variant (bf16 out), BK=64 double-buffered (32KB LDS).
// Used by KG (K=2048, 32 pipelined iters) and W3.
__global__ __launch_bounds__(256) void gemm64(
    const unsigned short* __restrict__ A, const unsigned short* __restrict__ Bt,
    unsigned short* __restrict__ C,
    int K, int Kstep, int lda, int ldb, int ldc,
    long Abs, long Bbs, long Cbs)
{
    __shared__ __align__(16) unsigned short As[2][64 * 64];
    __shared__ __align__(16) unsigned short Bs[2][64 * 64];
    int bz = blockIdx.z;
    int b = bz & 15, kc = bz >> 4;
    int m0 = blockIdx.y * 64, n0 = blockIdx.x * 64;
    const unsigned short* Ab = A + (size_t)b * Abs + (size_t)m0 * lda + (size_t)kc * Kstep;
    const unsigned short* Bb = Bt + (size_t)b * Bbs + (size_t)n0 * ldb + (size_t)kc * Kstep;
    int t = threadIdx.x;
    int w = t >> 6, l = t & 63, lm = l & 15, lq = l >> 4;
    int mw = (w >> 1) * 32, nw = (w & 1) * 32;

    f32x4 acc[2][2];
    f32x4 zero = {0.f, 0.f, 0.f, 0.f};
#pragma unroll
    for (int i = 0; i < 2; ++i)
#pragma unroll
        for (int j = 0; j < 2; ++j) acc[i][j] = zero;

    auto stage = [&](int buf, int kk) {
#pragma unroll
        for (int i = 0; i < 2; ++i) {
            int idx = t + i * 256;           // 0..511
            int r = idx >> 3;
            int sch = (idx & 7) ^ (r & 7);
            int lbase = (i * 256 + w * 64) * 8;
            gl_lds16(Ab + (size_t)r * lda + kk + sch * 8, &As[buf][lbase]);
            gl_lds16(Bb + (size_t)r * ldb + kk + sch * 8, &Bs[buf][lbase]);
        }
    };
    auto compute = [&](int buf) {
#pragma unroll
        for (int ks = 0; ks < 2; ++ks) {
            s16x8 af[2], bfr[2];
#pragma unroll
            for (int mi = 0; mi < 2; ++mi) {
                int row = mw + mi * 16 + lm;
                af[mi] = *(const s16x8*)&As[buf][row * 64 + (((ks * 4 + lq) ^ (row & 7)) << 3)];
            }
#pragma unroll
            for (int ni = 0; ni < 2; ++ni) {
                int row = nw + ni * 16 + lm;
                bfr[ni] = *(const s16x8*)&Bs[buf][row * 64 + (((ks * 4 + lq) ^ (row & 7)) << 3)];
            }
#pragma unroll
            for (int mi = 0; mi < 2; ++mi)
#pragma unroll
                for (int ni = 0; ni < 2; ++ni)
                    acc[mi][ni] = __builtin_amdgcn_mfma_f32_16x16x32_bf16(af[mi], bfr[ni], acc[mi][ni], 0, 0, 0);
        }
    };

    stage(0, 0);
    asm volatile("s_waitcnt vmcnt(0)" ::: "memory");
    __builtin_amdgcn_s_barrier();
    __builtin_amdgcn_sched_barrier(0);

    int cur = 0;
    for (int kk = 64; kk < K; kk += 64) {
        stage(cur ^ 1, kk);
        compute(cur);
        asm volatile("s_waitcnt vmcnt(0)" ::: "memory");
        __builtin_amdgcn_s_barrier();
        __builtin_amdgcn_sched_barrier(0);
        cur ^= 1;
    }
    compute(cur);

    unsigned short* Cb = C + (size_t)bz * Cbs;
#pragma unroll
    for (int mi = 0; mi < 2; ++mi)
#pragma unroll
        for (int r = 0; r < 4; ++r) {
            int m = m0 + mw + mi * 16 + lq * 4 + r;
#pragma unroll
            for (int ni = 0; ni < 2; ++ni) {
                int n = n0 + nw + ni * 16 + lm;
                Cb[(size_t)m * ldc + n] = f2bits(acc[mi][ni][r]);
            }
        }
}

// ---------------------------------------------------------------------------
// gemm_bt (fallback path only): reg-staged, padded LDS, optional f32 B.
template <int BF32, int EPI>
__global__ __launch_bounds__(256) void gemm_bt(
    const unsigned short* __restrict__ A, const void* __restrict__ Bt,
    void* __restrict__ C,
    int K, int Kstep, int lda, int ldb, int ldc,
    long Abs, long Bbs, long Cbs,
    const float* __restrict__ Xres,
    const float* __restrict__ gamma,
    const float* __restrict__ bias)
{
    __shared__ unsigned short As[128][72];
    __shared__ unsigned short Bs[128][72];
    int bz = blockIdx.z;
    int b = bz & 15, kc = bz >> 4;
    int m0 = blockIdx.y * 128, n0 = blockIdx.x * 128;
    const unsigned short* Ab = A + (size_t)b * Abs + (size_t)m0 * lda + (size_t)kc * Kstep;
    size_t boff = (size_t)b * Bbs + (size_t)n0 * ldb + (size_t)kc * Kstep;
    int t = threadIdx.x;
    int w = t >> 6, l = t & 63, lm = l & 15, lq = l >> 4;
    int mw = (w >> 1) * 64, nw = (w & 1) * 64;

    f32x4 acc[4][4];
    f32x4 zero = {0.f, 0.f, 0.f, 0.f};
#pragma unroll
    for (int i = 0; i < 4; ++i)
#pragma unroll
        for (int j = 0; j < 4; ++j) acc[i][j] = zero;

    for (int kk = 0; kk < K; kk += 64) {
#pragma unroll
        for (int i = 0; i < 4; ++i) {
            int idx = t + i * 256;
            int r = idx >> 3, ch = idx & 7;
            *(s16x8*)&As[r][ch * 8] = *(const s16x8*)(Ab + (size_t)r * lda + kk + ch * 8);
            if (BF32) {
                const float* bp = (const float*)Bt + boff + (size_t)r * ldb + kk + ch * 8;
                float4 v0 = *(const float4*)bp, v1 = *(const float4*)(bp + 4);
                unsigned int q[4] = { pack2(v0.x, v0.y), pack2(v0.z, v0.w),
                                      pack2(v1.x, v1.y), pack2(v1.z, v1.w) };
                *(s16x8*)&Bs[r][ch * 8] = *(s16x8*)q;
            } else {
                const unsigned short* bp = (const unsigned short*)Bt + boff + (size_t)r * ldb + kk + ch * 8;
                *(s16x8*)&Bs[r][ch * 8] = *(const s16x8*)bp;
            }
        }
        __syncthreads();
#pragma unroll
        for (int ks = 0; ks < 2; ++ks) {
            s16x8 af[4], bfr[4];
#pragma unroll
            for (int mi = 0; mi < 4; ++mi) af[mi]  = *(const s16x8*)&As[mw + mi * 16 + lm][ks * 32 + lq * 8];
#pragma unroll
            for (int ni = 0; ni < 4; ++ni) bfr[ni] = *(const s16x8*)&Bs[nw + ni * 16 + lm][ks * 32 + lq * 8];
#pragma unroll
            for (int mi = 0; mi < 4; ++mi)
#pragma unroll
                for (int ni = 0; ni < 4; ++ni)
                    acc[mi][ni] = __builtin_amdgcn_mfma_f32_16x16x32_bf16(af[mi], bfr[ni], acc[mi][ni], 0, 0, 0);
        }
        __syncthreads();
    }

    if (EPI == 0) {
        unsigned short* Cb = (unsigned short*)C + (size_t)bz * Cbs;
#pragma unroll
        for (int mi = 0; mi < 4; ++mi)
#pragma unroll
            for (int r = 0; r < 4; ++r) {
                int m = m0 + mw + mi * 16 + lq * 4 + r;
#pragma unroll
                for (int ni = 0; ni < 4; ++ni) {
                    int n = n0 + nw + ni * 16 + lm;
                    Cb[(size_t)m * ldc + n] = f2bits(acc[mi][ni][r]);
                }
            }
    } else {
        float* Cb = (float*)C + (size_t)bz * Cbs;
        const float* Xb = Xres + (size_t)bz * Cbs;
#pragma unroll
        for (int mi = 0; mi < 4; ++mi)
#pragma unroll
            for (int r = 0; r < 4; ++r) {
                int m = m0 + mw + mi * 16 + lq * 4 + r;
                float g = gamma[m], bo = bias[m];
#pragma unroll
                for (int ni = 0; ni < 4; ++ni) {
                    int n = n0 + nw + ni * 16 + lm;
                    size_t idx = (size_t)m * ldc + n;
                    Cb[idx] = g * (acc[mi][ni][r] + bo) + Xb[idx];
                }
            }
    }
}

// ---------------------------------------------------------------------------
// gemm_bn (fallback path only): C[m][n] = sum_k A[m][k] * B[k][n]
template <int EPI>
__global__ __launch_bounds__(256) void gemm_bn(
    const unsigned short* __restrict__ A, const float* __restrict__ B,
    void* __restrict__ C,
    int K, int lda, int ldb, int ldc,
    long Abs, long Bbs, long Cbs,
    const float* __restrict__ Xres,
    const float* __restrict__ gamma,
    const float* __restrict__ bias)
{
    __shared__ unsigned short As[128][72];
    __shared__ unsigned short Bs[64][130];
    int bz = blockIdx.z;
    int m0 = blockIdx.y * 128, n0 = blockIdx.x * 128;
    const unsigned short* Ab = A + (size_t)bz * Abs + (size_t)m0 * lda;
    const float* Bb = B + (size_t)bz * Bbs + n0;
    int t = threadIdx.x;
    int w = t >> 6, l = t & 63, lm = l & 15, lq = l >> 4;
    int mw = (w >> 1) * 64, nw = (w & 1) * 64;

    f32x4 acc[4][4];
    f32x4 zero = {0.f, 0.f, 0.f, 0.f};
#pragma unroll
    for (int i = 0; i < 4; ++i)
#pragma unroll
        for (int j = 0; j < 4; ++j) acc[i][j] = zero;

    for (int kk = 0; kk < K; kk += 64) {
#pragma unroll
        for (int i = 0; i < 4; ++i) {
            int idx = t + i * 256;
            int r = idx >> 3, ch = idx & 7;
            *(s16x8*)&As[r][ch * 8] = *(const s16x8*)(Ab + (size_t)r * lda + kk + ch * 8);
        }
#pragma unroll
        for (int i = 0; i < 4; ++i) {
            int idx = t + i * 256;
            int c = idx >> 4, cc = idx & 15;
            const float* bp = Bb + (size_t)(kk + c) * ldb + cc * 8;
            float4 v0 = *(const float4*)bp, v1 = *(const float4*)(bp + 4);
            unsigned int* q = (unsigned int*)&Bs[c][cc * 8];
            q[0] = pack2(v0.x, v0.y); q[1] = pack2(v0.z, v0.w);
            q[2] = pack2(v1.x, v1.y); q[3] = pack2(v1.z, v1.w);
        }
        __syncthreads();
#pragma unroll
        for (int ks = 0; ks < 2; ++ks) {
            s16x8 af[4];
#pragma unroll
            for (int mi = 0; mi < 4; ++mi) af[mi] = *(const s16x8*)&As[mw + mi * 16 + lm][ks * 32 + lq * 8];
#pragma unroll
            for (int ni = 0; ni < 4; ++ni) {
                s16x8 bfr;
#pragma unroll
                for (int j = 0; j < 8; ++j) bfr[j] = (short)Bs[ks * 32 + lq * 8 + j][nw + ni * 16 + lm];
#pragma unroll
                for (int mi = 0; mi < 4; ++mi)
                    acc[mi][ni] = __builtin_amdgcn_mfma_f32_16x16x32_bf16(af[mi], bfr, acc[mi][ni], 0, 0, 0);
            }
        }
        __syncthreads();
    }

#pragma unroll
    for (int mi = 0; mi < 4; ++mi)
#pragma unroll
        for (int r = 0; r < 4; ++r) {
            int m = m0 + mw + mi * 16 + lq * 4 + r;
            float g = 0.f, bo = 0.f;
            if (EPI == 1) { g = gamma[m]; bo = bias[m]; }
#pragma unroll
            for (int ni = 0; ni < 4; ++ni) {
                int n = n0 + nw + ni * 16 + lm;
                size_t idx = (size_t)m * ldc + n;
                float v = acc[mi][ni][r];
                if (EPI == 1) {
                    float* Cb = (float*)C + (size_t)bz * Cbs;
                    Cb[idx] = g * (v + bo) + Xres[(size_t)bz * Cbs + idx];
                } else {
                    unsigned short* Cb = (unsigned short*)C + (size_t)bz * Cbs;
                    Cb[idx] = f2bits(v);
                }
            }
        }
}

// ---------------------------------------------------------------------------
// softmax over n (4096) for each of 4096 rows of kbuf (bf16)
__global__ __launch_bounds__(256) void k_softmax(unsigned short* __restrict__ kbuf)
{
    unsigned short* p = kbuf + (size_t)blockIdx.x * 4096;
    int t = threadIdx.x;
    __shared__ float red[4];

    s16x8 r0 = *(const s16x8*)(p + t * 16);
    s16x8 r1 = *(const s16x8*)(p + t * 16 + 8);
    float v[16];
    float m = -1e30f;
#pragma unroll
    for (int i = 0; i < 8; ++i) { v[i] = bits2f((unsigned short)r0[i]); v[8 + i] = bits2f((unsigned short)r1[i]); }
#pragma unroll
    for (int i = 0; i < 16; ++i) m = fmaxf(m, v[i]);
#pragma unroll
    for (int off = 32; off >= 1; off >>= 1) m = fmaxf(m, __shfl_xor(m, off));
    if ((t & 63) == 0) red[t >> 6] = m;
    __syncthreads();
    m = fmaxf(fmaxf(red[0], red[1]), fmaxf(red[2], red[3]));
    __syncthreads();

    float s = 0.f;
#pragma unroll
    for (int i = 0; i < 16; ++i) { v[i] = __expf(v[i] - m); s += v[i]; }
#pragma unroll
    for (int off = 32; off >= 1; off >>= 1) s += __shfl_xor(s, off);
    if ((t & 63) == 0) red[t >> 6] = s;
    __syncthreads();
    s = red[0] + red[1] + red[2] + red[3];
    float inv = 1.0f / s;

    __align__(16) unsigned short otmp[16];
#pragma unroll
    for (int i = 0; i < 16; ++i) otmp[i] = f2bits(v[i] * inv);
    *(s16x8*)(p + t * 16) = *(s16x8*)(otmp);
    *(s16x8*)(p + t * 16 + 8) = *(s16x8*)(otmp + 8);
}

// ---------------------------------------------------------------------------
// G[b][i] = sum_{kc<NC} Gp[kc*16+b][i]
template <int NC>
__global__ __launch_bounds__(256) void k_gred(
    const unsigned short* __restrict__ Gp, unsigned short* __restrict__ G)
{
    int gid = blockIdx.x * 256 + threadIdx.x;   // [0, 131072)
    int b = gid >> 13;
    size_t i8 = (size_t)(gid & 8191) * 8;
    float s[8] = {0.f, 0.f, 0.f, 0.f, 0.f, 0.f, 0.f, 0.f};
#pragma unroll
    for (int kc = 0; kc < NC; ++kc) {
        s16x8 v = *(const s16x8*)(Gp + (size_t)(kc * 16 + b) * 65536 + i8);
#pragma unroll
        for (int j = 0; j < 8; ++j) s[j] += bits2f((unsigned short)v[j]);
    }
    __align__(16) unsigned short tmp[8];
#pragma unroll
    for (int j = 0; j < 8; ++j) tmp[j] = f2bits(s[j]);
    *(s16x8*)(G + (size_t)b * 65536 + i8) = *(s16x8*)tmp;
}

// ---------------------------------------------------------------------------
// per (b,h): ctx[d][e] = sum_c G[b][h*64+d][c] * Wv[h*64+e][c]  (K=256)
// then      W2[b][o][h*64+d] = sum_e w_out[o][h*64+e] * ctx[d][e] (K=64)
__global__ __launch_bounds__(256) void k_ctxw2(
    const unsigned short* __restrict__ G, const unsigned short* __restrict__ wb,
    const unsigned short* __restrict__ wob, unsigned short* __restrict__ W2)
{
    __shared__ unsigned short ctxs[64][72];
    int h = blockIdx.x, b = blockIdx.y;
    int t = threadIdx.x, w = t >> 6, l = t & 63, lm = l & 15, lq = l >> 4;
    const unsigned short* Gb = G + (size_t)b * 65536 + (size_t)(h * 64) * 256;
    const unsigned short* Wv = wb + 131072 + (size_t)(h * 64) * 256;
    f32x4 zero = {0.f, 0.f, 0.f, 0.f};

    f32x4 acc[4];
#pragma unroll
    for (int i = 0; i < 4; ++i) acc[i] = zero;
    for (int kk = 0; kk < 256; kk += 32) {
        s16x8 a = *(const s16x8*)(Gb + (size_t)(w * 16 + lm) * 256 + kk + lq * 8);
#pragma unroll
        for (int ni = 0; ni < 4; ++ni) {
            s16x8 bb = *(const s16x8*)(Wv + (size_t)(ni * 16 + lm) * 256 + kk + lq * 8);
            acc[ni] = __builtin_amdgcn_mfma_f32_16x16x32_bf16(a, bb, acc[ni], 0, 0, 0);
        }
    }
#pragma unroll
    for (int ni = 0; ni < 4; ++ni)
#pragma unroll
        for (int r = 0; r < 4; ++r)
            ctxs[w * 16 + lq * 4 + r][ni * 16 + lm] = f2bits(acc[ni][r]);
    __syncthreads();

    f32x4 acc2[4][4];
#pragma unroll
    for (int i = 0; i < 4; ++i)
#pragma unroll
        for (int j = 0; j < 4; ++j) acc2[i][j] = zero;
#pragma unroll
    for (int ks = 0; ks < 2; ++ks) {
        s16x8 af[4], bfr[4];
#pragma unroll
        for (int mi = 0; mi < 4; ++mi)
            af[mi] = *(const s16x8*)(wob + (size_t)(w * 64 + mi * 16 + lm) * 256 + h * 64 + ks * 32 + lq * 8);
#pragma unroll
        for (int ni = 0; ni < 4; ++ni) bfr[ni] = *(const s16x8*)&ctxs[ni * 16 + lm][ks * 32 + lq * 8];
#pragma unroll
        for (int mi = 0; mi < 4; ++mi)
#pragma unroll
            for (int ni = 0; ni < 4; ++ni)
                acc2[mi][ni] = __builtin_amdgcn_mfma_f32_16x16x32_bf16(af[mi], bfr[ni], acc2[mi][ni], 0, 0, 0);
    }
    unsigned short* W2b = W2 + (size_t)b * 65536;
#pragma unroll
    for (int mi = 0; mi < 4; ++mi)
#pragma unroll
        for (int r = 0; r < 4; ++r) {
            int o = w * 64 + mi * 16 + lq * 4 + r;
#pragma unroll
            for (int ni = 0; ni < 4; ++ni)
                W2b[(size_t)o * 256 + h * 64 + ni * 16 + lm] = f2bits(acc2[mi][ni][r]);
        }
}

// ---------------------------------------------------------------------------
extern "C" void kernel_launch(void* const* d_in, const int* in_sizes, int n_in,
                              void* d_out, int out_size, void* d_ws, size_t ws_size,
                              hipStream_t stream)
{
    (void)in_sizes; (void)n_in; (void)out_size;
    const float* x      = (const float*)d_in[0]; // [16][256][4096] f32
    const float* w_qkv  = (const float*)d_in[1]; // [768][256] f32
    const float* w_out  = (const float*)d_in[2]; // [256][256] f32
    const float* b_out  = (const float*)d_in[3]; // [256] f32
    const float* gamma  = (const float*)d_in[4]; // [256] f32

    char* ws = (char*)d_ws;
    const size_t NEED = 40501248;

    if (ws_size >= NEED) {
        // ws layout (40,501,248 B total):
        unsigned short* xT  = (unsigned short*)ws;                    // [16][4096][256] bf16 = 33,554,432
        unsigned short* W3  = (unsigned short*)(ws + 33554432);       //  2,097,152
        unsigned short* Gp  = (unsigned short*)(ws + 35651584);       //  4,194,304 (kc=2 split)
        unsigned short* WqT = (unsigned short*)(ws + 39845888);       //    131,072
        unsigned short* wb  = (unsigned short*)(ws + 39976960);       //    393,216
        unsigned short* wob = (unsigned short*)(ws + 40370176);       //    131,072
        // d_out (64MB) as scratch until K5 rewrites it:
        unsigned short* kbuf = (unsigned short*)d_out;                // [0, 32MB) — dead after KG
        unsigned short* xbf  = (unsigned short*)d_out + 16777216;     // [32MB, 64MB) — dead after KG
        unsigned short* G    = (unsigned short*)d_out;                // overlays dead kbuf (2MB)
        unsigned short* W2   = (unsigned short*)d_out + 1048576;      // +2MB (2MB) — dead before K5

        // weights: wb/wob bf16 + WqT
        k_prepw<<<dim3(160), 256, 0, stream>>>(w_qkv, w_out, wb, wob, WqT);

        // xT = transpose(x) bf16; xbf = x bf16 (same layout)
        k_prep<<<dim3(64, 16), 256, 0, stream>>>(x, xT, xbf);

        // K1: k = Wk @ x  == gemm_bt2(A=Wk, Bt=xT)   (M=256,N=4096,K=256)
        gemm_bt2<0><<<dim3(32, 2, 16), 256, 0, stream>>>(
            wb + 65536, xT, kbuf, 256, 0, 256, 256, 4096,
            0L, 1048576L, 1048576L, nullptr, nullptr, nullptr);

        // K2: softmax rows of k
        k_softmax<<<dim3(4096), 256, 0, stream>>>(kbuf);

        // KG: Gp[kc*16+b] = softk_b[:,chunk] @ xbf_b[:,chunk]^T (K-split x2, 64² tiles)
        gemm64<<<dim3(4, 4, 32), 256, 0, stream>>>(
            kbuf, xbf, Gp, 2048, 2048, 4096, 4096, 256,
            1048576L, 1048576L, 65536L);

        // G = sum_kc Gp  (G overlays dead kbuf region)
        k_gred<2><<<dim3(512), 256, 0, stream>>>(Gp, G);

        // ctx + W2 fused per (b,h)
        k_ctxw2<<<dim3(4, 16), 256, 0, stream>>>(G, wb, wob, W2);

        // W3[b] = W2[b] @ Wq
        gemm64<<<dim3(4, 4, 16), 256, 0, stream>>>(
            W2, WqT, W3, 256, 0, 256, 256, 256,
            65536L, 0L, 65536L);

        // K5: out(f32) = gamma*(W3 @ x + b_out) + x  == gemm_bt2<1>(A=W3, Bt=xT)
        gemm_bt2<1><<<dim3(32, 2, 16), 256, 0, stream>>>(
            W3, xT, d_out, 256, 0, 256, 256, 4096,
            65536L, 1048576L, 1048576L, x, gamma, b_out);
    } else {
        // ---- fallback: previously verified path (23,724,032 B of ws) ----
        unsigned short* kbuf = (unsigned short*)d_out;
        unsigned short* Gp  = (unsigned short*)(ws);                  // 16,777,216
        unsigned short* G   = (unsigned short*)(ws + 16777216);       //  2,097,152
        unsigned short* W2  = (unsigned short*)(ws + 18874368);       //  2,097,152
        unsigned short* W3  = (unsigned short*)(ws + 20971520);       //  2,097,152
        unsigned short* WqT = (unsigned short*)(ws + 23068672);       //    131,072
        unsigned short* wb  = (unsigned short*)(ws + 23199744);       //    393,216
        unsigned short* wob = (unsigned short*)(ws + 23592960);       //    131,072

        k_cvt<<<dim3(96), 256, 0, stream>>>(w_qkv, wb, 24576);
        k_cvt<<<dim3(32), 256, 0, stream>>>(w_out, wob, 8192);
        k_transpose<<<dim3(1, 32, 1), 256, 0, stream>>>(wb, WqT, 256, 256);

        gemm_bn<0><<<dim3(32, 2, 16), 256, 0, stream>>>(
            wb + 65536, x, kbuf, 256, 256, 4096, 4096,
            0L, 1048576L, 1048576L, nullptr, nullptr, nullptr);

        k_softmax<<<dim3(4096), 256, 0, stream>>>(kbuf);

        gemm_bt<1, 0><<<dim3(2, 2, 128), 256, 0, stream>>>(
            kbuf, x, Gp, 512, 512, 4096, 4096, 256,
            1048576L, 1048576L, 65536L, nullptr, nullptr, nullptr);

        k_gred<8><<<dim3(512), 256, 0, stream>>>(Gp, G);
        k_ctxw2<<<dim3(4, 16), 256, 0, stream>>>(G, wb, wob, W2);

        gemm_bt<0, 0><<<dim3(2, 2, 16), 256, 0, stream>>>(
            W2, WqT, W3, 256, 0, 256, 256, 256,
            65536L, 0L, 65536L, nullptr, nullptr, nullptr);

        gemm_bn<1><<<dim3(32, 2, 16), 256, 0, stream>>>(
            W3, x, d_out, 256, 256, 4096, 4096,
            65536L, 1048576L, 1048576L, x, gamma, b_out);
    }
}